// Round 1
// baseline (1536.911 us; speedup 1.0000x reference)
//
#include <hip/hip_runtime.h>
#include <math.h>

#define NTR 2048
#define MTE 4096
#define DIM 16
#define TT 4
#define NT 8192          // NTR * TT
#define KIT 64           // CG iterations

// workspace layout (float offsets)
#define OFF_KXX   0
#define OFF_A     (OFF_KXX + NTR*NTR)        // scaled train coords  N x D
#define OFF_ANORM (OFF_A + NTR*DIM)          // row norms            N
#define OFF_XS    (OFF_ANORM + NTR)          // scaled test coords   M x D
#define OFF_XNORM (OFF_XS + MTE*DIM)         // row norms            M
#define OFF_Y     (OFF_XNORM + MTE)          // rhs                  NT
#define OFF_X     (OFF_Y + NT)               // CG solution          NT
#define OFF_R     (OFF_X + NT)               // residual             NT
#define OFF_P0    (OFF_R + NT)               // direction buf 0      NT
#define OFF_P1    (OFF_P0 + NT)              // direction buf 1      NT
#define OFF_V     (OFF_P1 + NT)              // A*p                  NT
#define OFF_B     (OFF_V + NT)               // A_mat @ Kt           NT
#define OFF_RR    (OFF_B + NT)               // rr slots             KIT+1
#define OFF_PV    (OFF_RR + KIT + 1)         // p.v slots            KIT

__global__ void k_zero(float* __restrict__ slots, int n) {
    int i = blockIdx.x * blockDim.x + threadIdx.x;
    if (i < n) slots[i] = 0.f;
}

// one thread per train row: scaled coords, norms, rhs y = (ty - mc) interleaved,
// x = 0, r = y, rr[0] += y.y
__global__ void k_prep_train(const float* __restrict__ tx, const float* __restrict__ ty,
                             const float* __restrict__ ls, const float* __restrict__ mc,
                             float* __restrict__ a, float* __restrict__ anorm,
                             float* __restrict__ y, float* __restrict__ xv,
                             float* __restrict__ r, float* __restrict__ rr0) {
    int n = blockIdx.x * 256 + threadIdx.x;   // grid exactly covers NTR
    float an = 0.f;
    #pragma unroll
    for (int d = 0; d < DIM; ++d) {
        float v = tx[n*DIM + d] / ls[d];
        a[n*DIM + d] = v;
        an = fmaf(v, v, an);
    }
    anorm[n] = an;
    float4 yv;
    yv.x = ty[n*4+0] - mc[0];
    yv.y = ty[n*4+1] - mc[1];
    yv.z = ty[n*4+2] - mc[2];
    yv.w = ty[n*4+3] - mc[3];
    reinterpret_cast<float4*>(y)[n] = yv;
    reinterpret_cast<float4*>(r)[n] = yv;
    float4 z; z.x = z.y = z.z = z.w = 0.f;
    reinterpret_cast<float4*>(xv)[n] = z;
    float s = yv.x*yv.x + yv.y*yv.y + yv.z*yv.z + yv.w*yv.w;
    for (int off = 32; off > 0; off >>= 1) s += __shfl_down(s, off);
    if ((threadIdx.x & 63) == 0) atomicAdd(rr0, s);
}

__global__ void k_prep_test(const float* __restrict__ x, const float* __restrict__ ls,
                            float* __restrict__ xs, float* __restrict__ xnorm) {
    int m = blockIdx.x * 256 + threadIdx.x;   // grid exactly covers MTE
    float an = 0.f;
    #pragma unroll
    for (int d = 0; d < DIM; ++d) {
        float v = x[m*DIM + d] / ls[d];
        xs[m*DIM + d] = v;
        an = fmaf(v, v, an);
    }
    xnorm[m] = an;
}

// Kxx[i][j] = exp(-0.5 * max(|ai|^2 + |aj|^2 - 2 ai.aj, 0)), 64x64 tiles
__global__ __launch_bounds__(256) void k_kxx(const float* __restrict__ a,
                                             const float* __restrict__ anorm,
                                             float* __restrict__ Kxx) {
    __shared__ float ai[64][17];
    __shared__ float aj[64][17];
    __shared__ float ani[64], anj[64];
    int i0 = blockIdx.y * 64, j0 = blockIdx.x * 64;
    int tid = threadIdx.x;
    for (int idx = tid; idx < 64*DIM; idx += 256) {
        int rr_ = idx >> 4, d = idx & 15;
        ai[rr_][d] = a[(i0+rr_)*DIM + d];
        aj[rr_][d] = a[(j0+rr_)*DIM + d];
    }
    if (tid < 64) { ani[tid] = anorm[i0+tid]; anj[tid] = anorm[j0+tid]; }
    __syncthreads();
    int jl = tid & 63;
    int ib = (tid >> 6) * 16;
    for (int ii = 0; ii < 16; ++ii) {
        int il = ib + ii;
        float dot = 0.f;
        #pragma unroll
        for (int d = 0; d < DIM; ++d) dot = fmaf(ai[il][d], aj[jl][d], dot);
        float d2 = ani[il] + anj[jl] - 2.f*dot;
        Kxx[(size_t)(i0+il)*NTR + (j0+jl)] = expf(-0.5f * fmaxf(d2, 0.f));
    }
}

// CG kernel 1: p_new = r + beta*p_old;  q = p_new @ Kt (LDS, SoA);
// v[own rows] = Kxx_rows @ q + d .* p_new;  pv[k] += p_new.v (own rows)
__global__ __launch_bounds__(256) void k_cg_matvec(
    int k, const float* __restrict__ r, const float* __restrict__ p_old,
    float* __restrict__ p_new, float* __restrict__ v,
    const float* __restrict__ Kxx, const float* __restrict__ rr,
    float* __restrict__ pv_slot,
    const float* __restrict__ tf, const float* __restrict__ tv,
    const float* __restrict__ tn, const float* __restrict__ nz) {
    __shared__ float q[TT][NTR];      // 32 KB, SoA: conflict-free stride-1 reads
    __shared__ float ploc[8][TT];
    int tid = threadIdx.x;
    int row0 = blockIdx.x * 8;        // 256 blocks x 8 rows
    float f0 = tf[0], f1 = tf[1], f2 = tf[2], f3 = tf[3];
    float K00 = fmaf(f0,f0,tv[0]), K01 = f0*f1, K02 = f0*f2, K03 = f0*f3;
    float K11 = fmaf(f1,f1,tv[1]), K12 = f1*f2, K13 = f1*f3;
    float K22 = fmaf(f2,f2,tv[2]), K23 = f2*f3;
    float K33 = fmaf(f3,f3,tv[3]);
    float beta = 0.f;
    if (k > 0) {
        float num = rr[k], den = rr[k-1];
        beta = (den > 1e-30f) ? num / den : 0.f;
    }
    const float4* r4  = reinterpret_cast<const float4*>(r);
    const float4* po4 = reinterpret_cast<const float4*>(p_old);
    float4* pn4 = reinterpret_cast<float4*>(p_new);
    for (int j = tid; j < NTR; j += 256) {
        float4 rv = r4[j];
        float4 pvv;
        if (k > 0) pvv = po4[j]; else { pvv.x = pvv.y = pvv.z = pvv.w = 0.f; }
        float4 pn;
        pn.x = fmaf(beta, pvv.x, rv.x);
        pn.y = fmaf(beta, pvv.y, rv.y);
        pn.z = fmaf(beta, pvv.z, rv.z);
        pn.w = fmaf(beta, pvv.w, rv.w);
        q[0][j] = K00*pn.x + K01*pn.y + K02*pn.z + K03*pn.w;
        q[1][j] = K01*pn.x + K11*pn.y + K12*pn.z + K13*pn.w;
        q[2][j] = K02*pn.x + K12*pn.y + K22*pn.z + K23*pn.w;
        q[3][j] = K03*pn.x + K13*pn.y + K23*pn.z + K33*pn.w;
        pn4[j] = pn;
        int jl = j - row0;
        if (jl >= 0 && jl < 8) {
            ploc[jl][0] = pn.x; ploc[jl][1] = pn.y;
            ploc[jl][2] = pn.z; ploc[jl][3] = pn.w;
        }
    }
    __syncthreads();
    int wave = tid >> 6, lane = tid & 63;
    float dz = nz[0];
    float d0 = tn[0]+dz, d1 = tn[1]+dz, d2c = tn[2]+dz, d3 = tn[3]+dz;
    float pvw = 0.f;
    for (int pass = 0; pass < 2; ++pass) {
        int il = pass*4 + wave;
        int i = row0 + il;
        float a0 = 0.f, a1 = 0.f, a2 = 0.f, a3 = 0.f;
        const float* kr = Kxx + (size_t)i * NTR;
        for (int jb = 0; jb < 32; ++jb) {
            int j = jb*64 + lane;           // coalesced Kxx, conflict-free LDS
            float kv = kr[j];
            a0 = fmaf(kv, q[0][j], a0);
            a1 = fmaf(kv, q[1][j], a1);
            a2 = fmaf(kv, q[2][j], a2);
            a3 = fmaf(kv, q[3][j], a3);
        }
        for (int off = 32; off > 0; off >>= 1) {
            a0 += __shfl_down(a0, off);
            a1 += __shfl_down(a1, off);
            a2 += __shfl_down(a2, off);
            a3 += __shfl_down(a3, off);
        }
        if (lane == 0) {
            float4 vv;
            vv.x = fmaf(d0,  ploc[il][0], a0);
            vv.y = fmaf(d1,  ploc[il][1], a1);
            vv.z = fmaf(d2c, ploc[il][2], a2);
            vv.w = fmaf(d3,  ploc[il][3], a3);
            reinterpret_cast<float4*>(v)[i] = vv;
            pvw += vv.x*ploc[il][0] + vv.y*ploc[il][1]
                 + vv.z*ploc[il][2] + vv.w*ploc[il][3];
        }
    }
    if (lane == 0) atomicAdd(pv_slot, pvw);
}

// CG kernel 2: alpha = rr[k]/pv[k]; x += alpha p; r -= alpha v; rr[k+1] += r.r
__global__ void k_cg_update(const float* __restrict__ rrk, const float* __restrict__ pvk,
                            float* __restrict__ xv, float* __restrict__ r,
                            const float* __restrict__ p, const float* __restrict__ v,
                            float* __restrict__ rr_next) {
    int e = blockIdx.x * 256 + threadIdx.x;   // 2048 float4 groups = NT
    float pvv = pvk[0];
    float alpha = (fabsf(pvv) > 1e-30f) ? rrk[0] / pvv : 0.f;
    float4 x4 = reinterpret_cast<float4*>(xv)[e];
    float4 p4 = reinterpret_cast<const float4*>(p)[e];
    float4 r4 = reinterpret_cast<float4*>(r)[e];
    float4 v4 = reinterpret_cast<const float4*>(v)[e];
    x4.x = fmaf(alpha, p4.x, x4.x);  r4.x = fmaf(-alpha, v4.x, r4.x);
    x4.y = fmaf(alpha, p4.y, x4.y);  r4.y = fmaf(-alpha, v4.y, r4.y);
    x4.z = fmaf(alpha, p4.z, x4.z);  r4.z = fmaf(-alpha, v4.z, r4.z);
    x4.w = fmaf(alpha, p4.w, x4.w);  r4.w = fmaf(-alpha, v4.w, r4.w);
    reinterpret_cast<float4*>(xv)[e] = x4;
    reinterpret_cast<float4*>(r)[e]  = r4;
    float s = r4.x*r4.x + r4.y*r4.y + r4.z*r4.z + r4.w*r4.w;
    for (int off = 32; off > 0; off >>= 1) s += __shfl_down(s, off);
    if ((threadIdx.x & 63) == 0) atomicAdd(rr_next, s);
}

// B = A @ Kt  (A = alpha reshaped N x T; Kt symmetric)
__global__ void k_ab(const float* __restrict__ xv, const float* __restrict__ tf,
                     const float* __restrict__ tv, float* __restrict__ B) {
    int j = blockIdx.x * 256 + threadIdx.x;   // covers NTR
    float f0 = tf[0], f1 = tf[1], f2 = tf[2], f3 = tf[3];
    float K00 = fmaf(f0,f0,tv[0]), K01 = f0*f1, K02 = f0*f2, K03 = f0*f3;
    float K11 = fmaf(f1,f1,tv[1]), K12 = f1*f2, K13 = f1*f3;
    float K22 = fmaf(f2,f2,tv[2]), K23 = f2*f3;
    float K33 = fmaf(f3,f3,tv[3]);
    float4 x4 = reinterpret_cast<const float4*>(xv)[j];
    float4 b;
    b.x = K00*x4.x + K01*x4.y + K02*x4.z + K03*x4.w;
    b.y = K01*x4.x + K11*x4.y + K12*x4.z + K13*x4.w;
    b.z = K02*x4.x + K12*x4.y + K22*x4.z + K23*x4.w;
    b.w = K03*x4.x + K13*x4.y + K23*x4.z + K33*x4.w;
    reinterpret_cast<float4*>(B)[j] = b;
}

// mean[i,t] = mc[t] + sum_j exp(-0.5 d2(i,j)) * B[j,t]; Kxs computed on the fly
__global__ __launch_bounds__(256) void k_final(
    const float* __restrict__ xs, const float* __restrict__ xnorm,
    const float* __restrict__ a, const float* __restrict__ anorm,
    const float* __restrict__ B, const float* __restrict__ mc,
    float* __restrict__ out) {
    __shared__ float Bl[TT][NTR];     // 32 KB SoA
    int tid = threadIdx.x;
    for (int idx = tid; idx < NT; idx += 256)
        Bl[idx & 3][idx >> 2] = B[idx];
    __syncthreads();
    int wave = tid >> 6, lane = tid & 63;
    int i = blockIdx.x * 4 + wave;    // 1024 blocks x 4 waves = MTE rows
    float xr[DIM];
    #pragma unroll
    for (int d = 0; d < DIM; ++d) xr[d] = xs[i*DIM + d];
    float xn = xnorm[i];
    float a0 = 0.f, a1 = 0.f, a2 = 0.f, a3 = 0.f;
    for (int jb = 0; jb < 32; ++jb) {
        int j = jb*64 + lane;
        const float* ar = a + j*DIM;
        float dot = 0.f;
        #pragma unroll
        for (int d = 0; d < DIM; ++d) dot = fmaf(xr[d], ar[d], dot);
        float d2 = xn + anorm[j] - 2.f*dot;
        float e = expf(-0.5f * fmaxf(d2, 0.f));
        a0 = fmaf(e, Bl[0][j], a0);
        a1 = fmaf(e, Bl[1][j], a1);
        a2 = fmaf(e, Bl[2][j], a2);
        a3 = fmaf(e, Bl[3][j], a3);
    }
    for (int off = 32; off > 0; off >>= 1) {
        a0 += __shfl_down(a0, off);
        a1 += __shfl_down(a1, off);
        a2 += __shfl_down(a2, off);
        a3 += __shfl_down(a3, off);
    }
    if (lane == 0) {
        float4 o;
        o.x = mc[0] + a0; o.y = mc[1] + a1;
        o.z = mc[2] + a2; o.w = mc[3] + a3;
        reinterpret_cast<float4*>(out)[i] = o;
    }
}

extern "C" void kernel_launch(void* const* d_in, const int* in_sizes, int n_in,
                              void* d_out, int out_size, void* d_ws, size_t ws_size,
                              hipStream_t stream) {
    const float* x  = (const float*)d_in[0];
    const float* tx = (const float*)d_in[1];
    const float* ty = (const float*)d_in[2];
    const float* ls = (const float*)d_in[3];
    const float* mc = (const float*)d_in[4];
    const float* tf = (const float*)d_in[5];
    const float* tv = (const float*)d_in[6];
    const float* tn = (const float*)d_in[7];
    const float* nz = (const float*)d_in[8];

    float* ws    = (float*)d_ws;
    float* Kxx   = ws + OFF_KXX;
    float* a     = ws + OFF_A;
    float* anorm = ws + OFF_ANORM;
    float* xsb   = ws + OFF_XS;
    float* xnorm = ws + OFF_XNORM;
    float* y     = ws + OFF_Y;
    float* xv    = ws + OFF_X;
    float* r     = ws + OFF_R;
    float* p0    = ws + OFF_P0;
    float* p1    = ws + OFF_P1;
    float* v     = ws + OFF_V;
    float* B     = ws + OFF_B;
    float* rr    = ws + OFF_RR;
    float* pv    = ws + OFF_PV;

    k_zero<<<1, 256, 0, stream>>>(rr, 2*KIT + 1);            // rr + pv contiguous
    k_prep_train<<<NTR/256, 256, 0, stream>>>(tx, ty, ls, mc, a, anorm, y, xv, r, rr);
    k_prep_test<<<MTE/256, 256, 0, stream>>>(x, ls, xsb, xnorm);
    k_kxx<<<dim3(NTR/64, NTR/64), 256, 0, stream>>>(a, anorm, Kxx);

    for (int k = 0; k < KIT; ++k) {
        float* pcur = (k & 1) ? p1 : p0;
        float* pold = (k & 1) ? p0 : p1;
        k_cg_matvec<<<NTR/8, 256, 0, stream>>>(k, r, pold, pcur, v, Kxx, rr,
                                               pv + k, tf, tv, tn, nz);
        k_cg_update<<<NT/4/256, 256, 0, stream>>>(rr + k, pv + k, xv, r, pcur, v,
                                                  rr + k + 1);
    }

    k_ab<<<NTR/256, 256, 0, stream>>>(xv, tf, tv, B);
    k_final<<<MTE/4, 256, 0, stream>>>(xsb, xnorm, a, anorm, B, mc, (float*)d_out);
}

// Round 2
// 810.756 us; speedup vs baseline: 1.8957x; 1.8957x over previous
//
#include <hip/hip_runtime.h>
#include <hip/hip_cooperative_groups.h>
#include <math.h>

namespace cg = cooperative_groups;

#define NTR 2048
#define MTE 4096
#define DIM 16
#define TT 4
#define NT 8192          // NTR * TT
#define KIT 48           // max PIPECG iterations (early exit expected ~15)
#define NBLK 256         // persistent blocks (1 per CU)
#define ROWS 8           // train rows per block
#define TOL2 1e-9f       // early exit: gamma <= TOL2 * gamma0  (rel resid ~3e-5)

// workspace layout (float offsets)
#define OFF_A     0                       // scaled train coords  NTR x DIM
#define OFF_ANORM (OFF_A + NTR*DIM)       // row norms            NTR
#define OFF_R     (OFF_ANORM + NTR)       // initial residual (y) NT
#define OFF_W     (OFF_R + NT)            // w vector, x2 parity  2*NT
#define OFF_B     (OFF_W + 2*NT)          // A_mat @ Kt           NT
#define OFF_GP    (OFF_B + NT)            // gamma partials       2*NBLK
#define OFF_DP    (OFF_GP + 2*NBLK)      // delta partials       2*NBLK

__global__ void k_prep(const float* __restrict__ tx, const float* __restrict__ ty,
                       const float* __restrict__ ls, const float* __restrict__ mc,
                       float* __restrict__ a, float* __restrict__ anorm,
                       float* __restrict__ r) {
    int n = blockIdx.x * 256 + threadIdx.x;   // grid covers NTR exactly
    float an = 0.f;
    #pragma unroll
    for (int d = 0; d < DIM; ++d) {
        float v = tx[n*DIM + d] / ls[d];
        a[n*DIM + d] = v;
        an = fmaf(v, v, an);
    }
    anorm[n] = an;
    float4 yv;
    yv.x = ty[n*4+0] - mc[0];
    yv.y = ty[n*4+1] - mc[1];
    yv.z = ty[n*4+2] - mc[2];
    yv.w = ty[n*4+3] - mc[3];
    reinterpret_cast<float4*>(r)[n] = yv;
}

// Persistent pipelined-CG (Ghysels-Vanroose). One grid.sync per iteration.
// Block b owns train rows [8b, 8b+8) -> 32 interleaved vector elements.
// Kxx rows live in LDS (64KB); only w is shared globally (parity-double-buffered).
__global__ __launch_bounds__(256, 1) void k_pcg(
    const float* __restrict__ a, const float* __restrict__ anorm,
    const float* __restrict__ r0g, float* __restrict__ wbuf,
    float* __restrict__ gpart, float* __restrict__ dpart,
    float* __restrict__ Bout,
    const float* __restrict__ tf, const float* __restrict__ tv,
    const float* __restrict__ tn, const float* __restrict__ nz)
{
    __shared__ float KxxS[ROWS][NTR];      // 64 KB
    __shared__ float4 qS[NTR];             // 32 KB : Kt * w per train point
    __shared__ float arowS[ROWS][DIM];
    __shared__ float anormS[ROWS];
    __shared__ float uS[32];               // matvec result slice
    __shared__ float xS[32], rS[32], wS[32], pS[32], sS[32], zS[32];
    __shared__ float scal[2];

    cg::grid_group grid = cg::this_grid();
    const int tid = threadIdx.x;
    const int b = blockIdx.x;
    const int wv = tid >> 6, lane = tid & 63;
    const int i0 = b * ROWS;

    const float f0=tf[0], f1=tf[1], f2=tf[2], f3=tf[3];
    const float K00=fmaf(f0,f0,tv[0]), K01=f0*f1, K02=f0*f2, K03=f0*f3;
    const float K11=fmaf(f1,f1,tv[1]), K12=f1*f2, K13=f1*f3;
    const float K22=fmaf(f2,f2,tv[2]), K23=f2*f3;
    const float K33=fmaf(f3,f3,tv[3]);
    const float dz = nz[0];

    if (tid < ROWS*DIM) arowS[tid >> 4][tid & 15] = a[i0*DIM + tid];
    if (tid < ROWS) anormS[tid] = anorm[i0 + tid];
    if (tid < 32) {
        xS[tid]=0.f; pS[tid]=0.f; sS[tid]=0.f; zS[tid]=0.f;
        rS[tid] = r0g[i0*TT + tid];
    }
    __syncthreads();

    // build own Kxx rows in LDS (a is L2/L3-broadcast, ~128KB per block once)
    for (int j = tid; j < NTR; j += 256) {
        const float4* aj4 = reinterpret_cast<const float4*>(a + j*DIM);
        float4 A0=aj4[0], A1=aj4[1], A2=aj4[2], A3=aj4[3];
        float an = anorm[j];
        #pragma unroll
        for (int rr = 0; rr < ROWS; ++rr) {
            float dot;
            dot = arowS[rr][0]*A0.x;            dot = fmaf(arowS[rr][1], A0.y, dot);
            dot = fmaf(arowS[rr][2], A0.z, dot); dot = fmaf(arowS[rr][3], A0.w, dot);
            dot = fmaf(arowS[rr][4], A1.x, dot); dot = fmaf(arowS[rr][5], A1.y, dot);
            dot = fmaf(arowS[rr][6], A1.z, dot); dot = fmaf(arowS[rr][7], A1.w, dot);
            dot = fmaf(arowS[rr][8], A2.x, dot); dot = fmaf(arowS[rr][9], A2.y, dot);
            dot = fmaf(arowS[rr][10],A2.z, dot); dot = fmaf(arowS[rr][11],A2.w, dot);
            dot = fmaf(arowS[rr][12],A3.x, dot); dot = fmaf(arowS[rr][13],A3.y, dot);
            dot = fmaf(arowS[rr][14],A3.z, dot); dot = fmaf(arowS[rr][15],A3.w, dot);
            float d2 = anormS[rr] + an - 2.f*dot;
            KxxS[rr][j] = __expf(-0.5f * fmaxf(d2, 0.f));
        }
    }
    __syncthreads();

    // u_slice = (Kxx (x) Kt) * src   (diag added later by slice code)
    auto matvec = [&](const float4* __restrict__ src4) {
        for (int j = tid; j < NTR; j += 256) {
            float4 v = src4[j];
            float4 q;
            q.x = K00*v.x + K01*v.y + K02*v.z + K03*v.w;
            q.y = K01*v.x + K11*v.y + K12*v.z + K13*v.w;
            q.z = K02*v.x + K12*v.y + K22*v.z + K23*v.w;
            q.w = K03*v.x + K13*v.y + K23*v.z + K33*v.w;
            qS[j] = q;
        }
        __syncthreads();
        float a00=0,a01=0,a02=0,a03=0,a10=0,a11=0,a12=0,a13=0;
        const int r0_ = 2*wv, r1_ = r0_ + 1;
        for (int jb = 0; jb < NTR/64; ++jb) {
            int j = jb*64 + lane;
            float4 q = qS[j];
            float k0 = KxxS[r0_][j], k1 = KxxS[r1_][j];
            a00 = fmaf(k0,q.x,a00); a01 = fmaf(k0,q.y,a01);
            a02 = fmaf(k0,q.z,a02); a03 = fmaf(k0,q.w,a03);
            a10 = fmaf(k1,q.x,a10); a11 = fmaf(k1,q.y,a11);
            a12 = fmaf(k1,q.z,a12); a13 = fmaf(k1,q.w,a13);
        }
        #pragma unroll
        for (int off = 32; off; off >>= 1) {
            a00 += __shfl_down(a00,off); a01 += __shfl_down(a01,off);
            a02 += __shfl_down(a02,off); a03 += __shfl_down(a03,off);
            a10 += __shfl_down(a10,off); a11 += __shfl_down(a11,off);
            a12 += __shfl_down(a12,off); a13 += __shfl_down(a13,off);
        }
        if (lane == 0) {
            uS[r0_*4+0]=a00; uS[r0_*4+1]=a01; uS[r0_*4+2]=a02; uS[r0_*4+3]=a03;
            uS[r1_*4+0]=a10; uS[r1_*4+1]=a11; uS[r1_*4+2]=a12; uS[r1_*4+3]=a13;
        }
        __syncthreads();
    };

    // ---- init: w0 = A r0; gamma0 = (r,r); delta0 = (w,r) -> partial slots par=0
    matvec(reinterpret_cast<const float4*>(r0g));
    if (wv == 0) {
        float g = 0.f, dl = 0.f;
        if (lane < 32) {
            float rv = rS[lane];
            float wn = uS[lane] + (tn[lane & 3] + dz) * rv;
            wS[lane] = wn;
            wbuf[i0*TT + lane] = wn;            // parity 0
            g = rv * rv;
            dl = wn * rv;
        }
        #pragma unroll
        for (int off = 32; off; off >>= 1) { g += __shfl_down(g,off); dl += __shfl_down(dl,off); }
        if (lane == 0) { gpart[b] = g; dpart[b] = dl; }
    }
    __threadfence();
    grid.sync();

    // ---- main loop: 1 grid.sync per iteration
    float alpha_prev = 1.f, gamma_prev = 1.f, gamma0 = 0.f;
    for (int k = 0; k < KIT; ++k) {
        const int par = k & 1;
        // deterministic fixed-order reduction of the 256 partials
        if (wv == 0) {
            float g = 0.f, dl = 0.f;
            for (int t = lane; t < NBLK; t += 64) {
                g  += gpart[par*NBLK + t];
                dl += dpart[par*NBLK + t];
            }
            #pragma unroll
            for (int off = 32; off; off >>= 1) { g += __shfl_down(g,off); dl += __shfl_down(dl,off); }
            if (lane == 0) { scal[0] = g; scal[1] = dl; }
        }
        __syncthreads();
        float gam = scal[0], del = scal[1];
        if (k == 0) gamma0 = gam;
        if (k > 0 && gam <= TOL2 * gamma0) break;   // uniform across grid
        float beta, alph;
        if (k == 0) { beta = 0.f; alph = gam / del; }
        else {
            beta = gam / gamma_prev;
            alph = gam / (del - beta * gam / alpha_prev);
        }

        matvec(reinterpret_cast<const float4*>(wbuf + par*NT));   // u = A*w (kron part)

        if (wv == 0) {
            float g = 0.f, dl = 0.f;
            if (lane < 32) {
                float wv_ = wS[lane];
                float u  = uS[lane] + (tn[lane & 3] + dz) * wv_;  // + diag
                float z  = fmaf(beta, zS[lane], u);
                float s  = fmaf(beta, sS[lane], wv_);
                float p  = fmaf(beta, pS[lane], rS[lane]);
                float x  = fmaf(alph, p, xS[lane]);
                float rn = fmaf(-alph, s, rS[lane]);
                float wn = fmaf(-alph, z, wv_);
                zS[lane]=z; sS[lane]=s; pS[lane]=p;
                xS[lane]=x; rS[lane]=rn; wS[lane]=wn;
                wbuf[(par^1)*NT + i0*TT + lane] = wn;
                g = rn*rn; dl = wn*rn;
            }
            #pragma unroll
            for (int off = 32; off; off >>= 1) { g += __shfl_down(g,off); dl += __shfl_down(dl,off); }
            if (lane == 0) { gpart[(par^1)*NBLK + b] = g; dpart[(par^1)*NBLK + b] = dl; }
        }
        gamma_prev = gam; alpha_prev = alph;
        __threadfence();
        grid.sync();
    }

    // ---- tail: B slice = (x reshaped N x T) @ Kt  (slice-local)
    __syncthreads();
    if (tid < ROWS) {
        float x0 = xS[tid*4+0], x1 = xS[tid*4+1], x2 = xS[tid*4+2], x3 = xS[tid*4+3];
        float4 Bv;
        Bv.x = K00*x0 + K01*x1 + K02*x2 + K03*x3;
        Bv.y = K01*x0 + K11*x1 + K12*x2 + K13*x3;
        Bv.z = K02*x0 + K12*x1 + K22*x2 + K23*x3;
        Bv.w = K03*x0 + K13*x1 + K23*x2 + K33*x3;
        reinterpret_cast<float4*>(Bout)[i0 + tid] = Bv;
    }
}

// mean[i,t] = mc[t] + sum_j exp(-0.5 d2(i,j)) * B[j,t]
// 16 test rows per block (4 per wave); a[j] register-cached across the 4 rows.
__global__ __launch_bounds__(256) void k_final(
    const float* __restrict__ x, const float* __restrict__ ls,
    const float* __restrict__ a, const float* __restrict__ anorm,
    const float* __restrict__ B, const float* __restrict__ mc,
    float* __restrict__ out)
{
    __shared__ float4 Bl[NTR];             // 32 KB
    __shared__ float xrS[16][DIM];
    __shared__ float xnS[16];
    int tid = threadIdx.x;
    int rbase = blockIdx.x * 16;
    for (int j = tid; j < NTR; j += 256)
        Bl[j] = reinterpret_cast<const float4*>(B)[j];
    {
        int row = tid >> 4, d = tid & 15;  // 256 threads = 16 rows x 16 dims
        float v = x[(rbase + row)*DIM + d] / ls[d];
        xrS[row][d] = v;
    }
    __syncthreads();
    if (tid < 16) {
        float s = 0.f;
        #pragma unroll
        for (int d = 0; d < DIM; ++d) s = fmaf(xrS[tid][d], xrS[tid][d], s);
        xnS[tid] = s;
    }
    __syncthreads();
    int wv = tid >> 6, lane = tid & 63;
    float acc[4][4];
    #pragma unroll
    for (int i = 0; i < 4; ++i)
        #pragma unroll
        for (int t = 0; t < 4; ++t) acc[i][t] = 0.f;
    for (int jb = 0; jb < NTR/64; ++jb) {
        int j = jb*64 + lane;
        const float4* aj4 = reinterpret_cast<const float4*>(a + j*DIM);
        float4 A0=aj4[0], A1=aj4[1], A2=aj4[2], A3=aj4[3];
        float an = anorm[j];
        float4 Bj = Bl[j];
        #pragma unroll
        for (int rr = 0; rr < 4; ++rr) {
            int row = 4*wv + rr;
            float dot;
            dot = xrS[row][0]*A0.x;             dot = fmaf(xrS[row][1], A0.y, dot);
            dot = fmaf(xrS[row][2], A0.z, dot);  dot = fmaf(xrS[row][3], A0.w, dot);
            dot = fmaf(xrS[row][4], A1.x, dot);  dot = fmaf(xrS[row][5], A1.y, dot);
            dot = fmaf(xrS[row][6], A1.z, dot);  dot = fmaf(xrS[row][7], A1.w, dot);
            dot = fmaf(xrS[row][8], A2.x, dot);  dot = fmaf(xrS[row][9], A2.y, dot);
            dot = fmaf(xrS[row][10],A2.z, dot);  dot = fmaf(xrS[row][11],A2.w, dot);
            dot = fmaf(xrS[row][12],A3.x, dot);  dot = fmaf(xrS[row][13],A3.y, dot);
            dot = fmaf(xrS[row][14],A3.z, dot);  dot = fmaf(xrS[row][15],A3.w, dot);
            float d2 = xnS[row] + an - 2.f*dot;
            float e = __expf(-0.5f * fmaxf(d2, 0.f));
            acc[rr][0] = fmaf(e, Bj.x, acc[rr][0]);
            acc[rr][1] = fmaf(e, Bj.y, acc[rr][1]);
            acc[rr][2] = fmaf(e, Bj.z, acc[rr][2]);
            acc[rr][3] = fmaf(e, Bj.w, acc[rr][3]);
        }
    }
    #pragma unroll
    for (int off = 32; off; off >>= 1)
        #pragma unroll
        for (int rr = 0; rr < 4; ++rr) {
            acc[rr][0] += __shfl_down(acc[rr][0], off);
            acc[rr][1] += __shfl_down(acc[rr][1], off);
            acc[rr][2] += __shfl_down(acc[rr][2], off);
            acc[rr][3] += __shfl_down(acc[rr][3], off);
        }
    if (lane == 0) {
        float m0 = mc[0], m1 = mc[1], m2 = mc[2], m3 = mc[3];
        #pragma unroll
        for (int rr = 0; rr < 4; ++rr) {
            float4 o;
            o.x = m0 + acc[rr][0]; o.y = m1 + acc[rr][1];
            o.z = m2 + acc[rr][2]; o.w = m3 + acc[rr][3];
            reinterpret_cast<float4*>(out)[rbase + 4*wv + rr] = o;
        }
    }
}

extern "C" void kernel_launch(void* const* d_in, const int* in_sizes, int n_in,
                              void* d_out, int out_size, void* d_ws, size_t ws_size,
                              hipStream_t stream) {
    const float* x  = (const float*)d_in[0];
    const float* tx = (const float*)d_in[1];
    const float* ty = (const float*)d_in[2];
    const float* ls = (const float*)d_in[3];
    const float* mc = (const float*)d_in[4];
    const float* tf = (const float*)d_in[5];
    const float* tv = (const float*)d_in[6];
    const float* tn = (const float*)d_in[7];
    const float* nz = (const float*)d_in[8];

    float* ws    = (float*)d_ws;
    float* a     = ws + OFF_A;
    float* anorm = ws + OFF_ANORM;
    float* r     = ws + OFF_R;
    float* w     = ws + OFF_W;
    float* B     = ws + OFF_B;
    float* gp    = ws + OFF_GP;
    float* dp    = ws + OFF_DP;

    k_prep<<<NTR/256, 256, 0, stream>>>(tx, ty, ls, mc, a, anorm, r);

    void* args[] = { (void*)&a, (void*)&anorm, (void*)&r, (void*)&w,
                     (void*)&gp, (void*)&dp, (void*)&B,
                     (void*)&tf, (void*)&tv, (void*)&tn, (void*)&nz };
    hipLaunchCooperativeKernel((void*)k_pcg, dim3(NBLK), dim3(256), args, 0, stream);

    k_final<<<MTE/16, 256, 0, stream>>>(x, ls, a, anorm, B, mc, (float*)d_out);
}

// Round 3
// 639.475 us; speedup vs baseline: 2.4034x; 1.2678x over previous
//
#include <hip/hip_runtime.h>
#include <math.h>

#define NTR 2048
#define MTE 4096
#define DIM 16
#define TT 4
#define NT 8192          // NTR * TT
#define KIT 40           // max PIPECG iterations (early exit expected ~17-22)
#define NBLK 256         // persistent blocks (1 per CU)
#define ROWS 8           // train rows per block
#define TOL2 1e-9f       // early exit: gamma <= TOL2 * gamma0
#define FSTR 32          // flag stride in ints (128 B)

// workspace layout (float offsets)
#define OFF_A     0                       // scaled train coords  NTR x DIM
#define OFF_ANORM (OFF_A + NTR*DIM)       // row norms            NTR
#define OFF_R     (OFF_ANORM + NTR)       // initial residual (y) NT
#define OFF_W     (OFF_R + NT)            // w vector, x2 parity  2*NT
#define OFF_B     (OFF_W + 2*NT)          // A_mat @ Kt           NT
#define OFF_GP    (OFF_B + NT)            // gamma partials       2*NBLK
#define OFF_DP    (OFF_GP + 2*NBLK)       // delta partials       2*NBLK
#define OFF_FLAGS (OFF_DP + 2*NBLK)       // barrier flags        NBLK*FSTR ints

__global__ void k_prep(const float* __restrict__ tx, const float* __restrict__ ty,
                       const float* __restrict__ ls, const float* __restrict__ mc,
                       float* __restrict__ a, float* __restrict__ anorm,
                       float* __restrict__ r, int* __restrict__ flags) {
    int n = blockIdx.x * 256 + threadIdx.x;   // grid covers NTR exactly
    // zero barrier flags: 2048 threads x int4 = 8192 ints = NBLK*FSTR
    reinterpret_cast<int4*>(flags)[n] = make_int4(0, 0, 0, 0);
    float an = 0.f;
    #pragma unroll
    for (int d = 0; d < DIM; ++d) {
        float v = tx[n*DIM + d] / ls[d];
        a[n*DIM + d] = v;
        an = fmaf(v, v, an);
    }
    anorm[n] = an;
    float4 yv;
    yv.x = ty[n*4+0] - mc[0];
    yv.y = ty[n*4+1] - mc[1];
    yv.z = ty[n*4+2] - mc[2];
    yv.w = ty[n*4+3] - mc[3];
    reinterpret_cast<float4*>(r)[n] = yv;
}

// 1-hop grid barrier: block publishes gen to its own flag; every thread spins
// on one flag. Monotonic generations -> no reset race; flags zeroed by k_prep.
__device__ __forceinline__ void gbar(int* __restrict__ flags, int b, int tid, int gen) {
    __threadfence();               // release own writes (L1 write-through; L2 flush)
    __syncthreads();               // all waves of block done + fenced
    if (tid == 0)
        __hip_atomic_store(flags + b*FSTR, gen, __ATOMIC_RELEASE, __HIP_MEMORY_SCOPE_AGENT);
    while (__hip_atomic_load(flags + tid*FSTR, __ATOMIC_RELAXED, __HIP_MEMORY_SCOPE_AGENT) < gen)
        __builtin_amdgcn_s_sleep(1);
    __syncthreads();
    __threadfence();               // acquire: drop stale cached lines
}

// Persistent pipelined-CG (Ghysels-Vanroose). One barrier per iteration.
// Block b owns train rows [8b, 8b+8) -> 32 interleaved vector elements.
// Kxx rows live in LDS (64KB); only w is shared globally (parity-double-buffered).
__global__ __launch_bounds__(256, 1) void k_pcg(
    const float* __restrict__ a, const float* __restrict__ anorm,
    const float* __restrict__ r0g, float* __restrict__ wbuf,
    float* __restrict__ gpart, float* __restrict__ dpart,
    float* __restrict__ Bout, int* __restrict__ flags,
    const float* __restrict__ tf, const float* __restrict__ tv,
    const float* __restrict__ tn, const float* __restrict__ nz)
{
    __shared__ float KxxS[ROWS][NTR];      // 64 KB
    __shared__ float4 qS[NTR];             // 32 KB : Kt * w per train point
    __shared__ float arowS[ROWS][DIM];
    __shared__ float anormS[ROWS];
    __shared__ float uS[32];               // matvec result slice
    __shared__ float xS[32], rS[32], wS[32], pS[32], sS[32], zS[32];
    __shared__ float scal[2];

    const int tid = threadIdx.x;
    const int b = blockIdx.x;
    const int wv = tid >> 6, lane = tid & 63;
    const int i0 = b * ROWS;
    int gen = 0;

    const float f0=tf[0], f1=tf[1], f2=tf[2], f3=tf[3];
    const float K00=fmaf(f0,f0,tv[0]), K01=f0*f1, K02=f0*f2, K03=f0*f3;
    const float K11=fmaf(f1,f1,tv[1]), K12=f1*f2, K13=f1*f3;
    const float K22=fmaf(f2,f2,tv[2]), K23=f2*f3;
    const float K33=fmaf(f3,f3,tv[3]);
    const float dz = nz[0];

    if (tid < ROWS*DIM) arowS[tid >> 4][tid & 15] = a[i0*DIM + tid];
    if (tid < ROWS) anormS[tid] = anorm[i0 + tid];
    if (tid < 32) {
        xS[tid]=0.f; pS[tid]=0.f; sS[tid]=0.f; zS[tid]=0.f;
        rS[tid] = r0g[i0*TT + tid];
    }
    __syncthreads();

    // build own Kxx rows in LDS (a is L2/L3-broadcast, ~128KB per block once)
    for (int j = tid; j < NTR; j += 256) {
        const float4* aj4 = reinterpret_cast<const float4*>(a + j*DIM);
        float4 A0=aj4[0], A1=aj4[1], A2=aj4[2], A3=aj4[3];
        float an = anorm[j];
        #pragma unroll
        for (int rr = 0; rr < ROWS; ++rr) {
            float dot;
            dot = arowS[rr][0]*A0.x;            dot = fmaf(arowS[rr][1], A0.y, dot);
            dot = fmaf(arowS[rr][2], A0.z, dot); dot = fmaf(arowS[rr][3], A0.w, dot);
            dot = fmaf(arowS[rr][4], A1.x, dot); dot = fmaf(arowS[rr][5], A1.y, dot);
            dot = fmaf(arowS[rr][6], A1.z, dot); dot = fmaf(arowS[rr][7], A1.w, dot);
            dot = fmaf(arowS[rr][8], A2.x, dot); dot = fmaf(arowS[rr][9], A2.y, dot);
            dot = fmaf(arowS[rr][10],A2.z, dot); dot = fmaf(arowS[rr][11],A2.w, dot);
            dot = fmaf(arowS[rr][12],A3.x, dot); dot = fmaf(arowS[rr][13],A3.y, dot);
            dot = fmaf(arowS[rr][14],A3.z, dot); dot = fmaf(arowS[rr][15],A3.w, dot);
            float d2 = anormS[rr] + an - 2.f*dot;
            KxxS[rr][j] = __expf(-0.5f * fmaxf(d2, 0.f));
        }
    }
    __syncthreads();

    // u_slice = (Kxx (x) Kt) * src   (diag added later by slice code)
    auto matvec = [&](const float4* __restrict__ src4) {
        for (int j = tid; j < NTR; j += 256) {
            float4 v = src4[j];
            float4 q;
            q.x = K00*v.x + K01*v.y + K02*v.z + K03*v.w;
            q.y = K01*v.x + K11*v.y + K12*v.z + K13*v.w;
            q.z = K02*v.x + K12*v.y + K22*v.z + K23*v.w;
            q.w = K03*v.x + K13*v.y + K23*v.z + K33*v.w;
            qS[j] = q;
        }
        __syncthreads();
        float a00=0,a01=0,a02=0,a03=0,a10=0,a11=0,a12=0,a13=0;
        const int r0_ = 2*wv, r1_ = r0_ + 1;
        for (int jb = 0; jb < NTR/64; ++jb) {
            int j = jb*64 + lane;
            float4 q = qS[j];
            float k0 = KxxS[r0_][j], k1 = KxxS[r1_][j];
            a00 = fmaf(k0,q.x,a00); a01 = fmaf(k0,q.y,a01);
            a02 = fmaf(k0,q.z,a02); a03 = fmaf(k0,q.w,a03);
            a10 = fmaf(k1,q.x,a10); a11 = fmaf(k1,q.y,a11);
            a12 = fmaf(k1,q.z,a12); a13 = fmaf(k1,q.w,a13);
        }
        #pragma unroll
        for (int off = 32; off; off >>= 1) {
            a00 += __shfl_down(a00,off); a01 += __shfl_down(a01,off);
            a02 += __shfl_down(a02,off); a03 += __shfl_down(a03,off);
            a10 += __shfl_down(a10,off); a11 += __shfl_down(a11,off);
            a12 += __shfl_down(a12,off); a13 += __shfl_down(a13,off);
        }
        if (lane == 0) {
            uS[r0_*4+0]=a00; uS[r0_*4+1]=a01; uS[r0_*4+2]=a02; uS[r0_*4+3]=a03;
            uS[r1_*4+0]=a10; uS[r1_*4+1]=a11; uS[r1_*4+2]=a12; uS[r1_*4+3]=a13;
        }
        __syncthreads();
    };

    // ---- init: w0 = A r0; gamma0 = (r,r); delta0 = (w,r) -> partial slots par=0
    matvec(reinterpret_cast<const float4*>(r0g));
    if (wv == 0) {
        float g = 0.f, dl = 0.f;
        if (lane < 32) {
            float rv = rS[lane];
            float wn = uS[lane] + (tn[lane & 3] + dz) * rv;
            wS[lane] = wn;
            wbuf[i0*TT + lane] = wn;            // parity 0
            g = rv * rv;
            dl = wn * rv;
        }
        #pragma unroll
        for (int off = 32; off; off >>= 1) { g += __shfl_down(g,off); dl += __shfl_down(dl,off); }
        if (lane == 0) { gpart[b] = g; dpart[b] = dl; }
    }
    gbar(flags, b, tid, ++gen);

    // ---- main loop: 1 barrier per iteration
    float alpha_prev = 1.f, gamma_prev = 1.f, gamma0 = 0.f;
    float g1 = 1e30f, g2 = 1e30f, g3 = 1e30f;   // gamma history (k-1,k-2,k-3)
    for (int k = 0; k < KIT; ++k) {
        const int par = k & 1;
        // deterministic fixed-order reduction of the 256 partials (replicated)
        if (wv == 0) {
            float g = 0.f, dl = 0.f;
            for (int t = lane; t < NBLK; t += 64) {
                g  += gpart[par*NBLK + t];
                dl += dpart[par*NBLK + t];
            }
            #pragma unroll
            for (int off = 32; off; off >>= 1) { g += __shfl_down(g,off); dl += __shfl_down(dl,off); }
            if (lane == 0) { scal[0] = g; scal[1] = dl; }
        }
        __syncthreads();
        float gam = scal[0], del = scal[1];
        if (k == 0) gamma0 = gam;
        // early exit: converged OR fp32 stagnation (uniform decision grid-wide)
        if (k > 0 && gam <= TOL2 * gamma0) break;
        if (k >= 12 && gam > 0.30f * g3) break;
        float beta, alph;
        if (k == 0) { beta = 0.f; alph = gam / del; }
        else {
            beta = gam / gamma_prev;
            alph = gam / (del - beta * gam / alpha_prev);
        }

        matvec(reinterpret_cast<const float4*>(wbuf + par*NT));   // u = A*w (kron part)

        if (wv == 0) {
            float g = 0.f, dl = 0.f;
            if (lane < 32) {
                float wv_ = wS[lane];
                float u  = uS[lane] + (tn[lane & 3] + dz) * wv_;  // + diag
                float z  = fmaf(beta, zS[lane], u);
                float s  = fmaf(beta, sS[lane], wv_);
                float p  = fmaf(beta, pS[lane], rS[lane]);
                float x  = fmaf(alph, p, xS[lane]);
                float rn = fmaf(-alph, s, rS[lane]);
                float wn = fmaf(-alph, z, wv_);
                zS[lane]=z; sS[lane]=s; pS[lane]=p;
                xS[lane]=x; rS[lane]=rn; wS[lane]=wn;
                wbuf[(par^1)*NT + i0*TT + lane] = wn;
                g = rn*rn; dl = wn*rn;
            }
            #pragma unroll
            for (int off = 32; off; off >>= 1) { g += __shfl_down(g,off); dl += __shfl_down(dl,off); }
            if (lane == 0) { gpart[(par^1)*NBLK + b] = g; dpart[(par^1)*NBLK + b] = dl; }
        }
        gamma_prev = gam; alpha_prev = alph;
        g3 = g2; g2 = g1; g1 = gam;
        gbar(flags, b, tid, ++gen);
    }

    // ---- tail: B slice = (x reshaped N x T) @ Kt  (slice-local)
    __syncthreads();
    if (tid < ROWS) {
        float x0 = xS[tid*4+0], x1 = xS[tid*4+1], x2 = xS[tid*4+2], x3 = xS[tid*4+3];
        float4 Bv;
        Bv.x = K00*x0 + K01*x1 + K02*x2 + K03*x3;
        Bv.y = K01*x0 + K11*x1 + K12*x2 + K13*x3;
        Bv.z = K02*x0 + K12*x1 + K22*x2 + K23*x3;
        Bv.w = K03*x0 + K13*x1 + K23*x2 + K33*x3;
        reinterpret_cast<float4*>(Bout)[i0 + tid] = Bv;
    }
}

// mean[i,t] = mc[t] + sum_j exp(-0.5 d2(i,j)) * B[j,t]
// 16 test rows per block (4 per wave); a[j] register-cached across the 4 rows.
__global__ __launch_bounds__(256) void k_final(
    const float* __restrict__ x, const float* __restrict__ ls,
    const float* __restrict__ a, const float* __restrict__ anorm,
    const float* __restrict__ B, const float* __restrict__ mc,
    float* __restrict__ out)
{
    __shared__ float4 Bl[NTR];             // 32 KB
    __shared__ float xrS[16][DIM];
    __shared__ float xnS[16];
    int tid = threadIdx.x;
    int rbase = blockIdx.x * 16;
    for (int j = tid; j < NTR; j += 256)
        Bl[j] = reinterpret_cast<const float4*>(B)[j];
    {
        int row = tid >> 4, d = tid & 15;  // 256 threads = 16 rows x 16 dims
        float v = x[(rbase + row)*DIM + d] / ls[d];
        xrS[row][d] = v;
    }
    __syncthreads();
    if (tid < 16) {
        float s = 0.f;
        #pragma unroll
        for (int d = 0; d < DIM; ++d) s = fmaf(xrS[tid][d], xrS[tid][d], s);
        xnS[tid] = s;
    }
    __syncthreads();
    int wv = tid >> 6, lane = tid & 63;
    float acc[4][4];
    #pragma unroll
    for (int i = 0; i < 4; ++i)
        #pragma unroll
        for (int t = 0; t < 4; ++t) acc[i][t] = 0.f;
    for (int jb = 0; jb < NTR/64; ++jb) {
        int j = jb*64 + lane;
        const float4* aj4 = reinterpret_cast<const float4*>(a + j*DIM);
        float4 A0=aj4[0], A1=aj4[1], A2=aj4[2], A3=aj4[3];
        float an = anorm[j];
        float4 Bj = Bl[j];
        #pragma unroll
        for (int rr = 0; rr < 4; ++rr) {
            int row = 4*wv + rr;
            float dot;
            dot = xrS[row][0]*A0.x;             dot = fmaf(xrS[row][1], A0.y, dot);
            dot = fmaf(xrS[row][2], A0.z, dot);  dot = fmaf(xrS[row][3], A0.w, dot);
            dot = fmaf(xrS[row][4], A1.x, dot);  dot = fmaf(xrS[row][5], A1.y, dot);
            dot = fmaf(xrS[row][6], A1.z, dot);  dot = fmaf(xrS[row][7], A1.w, dot);
            dot = fmaf(xrS[row][8], A2.x, dot);  dot = fmaf(xrS[row][9], A2.y, dot);
            dot = fmaf(xrS[row][10],A2.z, dot);  dot = fmaf(xrS[row][11],A2.w, dot);
            dot = fmaf(xrS[row][12],A3.x, dot);  dot = fmaf(xrS[row][13],A3.y, dot);
            dot = fmaf(xrS[row][14],A3.z, dot);  dot = fmaf(xrS[row][15],A3.w, dot);
            float d2 = xnS[row] + an - 2.f*dot;
            float e = __expf(-0.5f * fmaxf(d2, 0.f));
            acc[rr][0] = fmaf(e, Bj.x, acc[rr][0]);
            acc[rr][1] = fmaf(e, Bj.y, acc[rr][1]);
            acc[rr][2] = fmaf(e, Bj.z, acc[rr][2]);
            acc[rr][3] = fmaf(e, Bj.w, acc[rr][3]);
        }
    }
    #pragma unroll
    for (int off = 32; off; off >>= 1)
        #pragma unroll
        for (int rr = 0; rr < 4; ++rr) {
            acc[rr][0] += __shfl_down(acc[rr][0], off);
            acc[rr][1] += __shfl_down(acc[rr][1], off);
            acc[rr][2] += __shfl_down(acc[rr][2], off);
            acc[rr][3] += __shfl_down(acc[rr][3], off);
        }
    if (lane == 0) {
        float m0 = mc[0], m1 = mc[1], m2 = mc[2], m3 = mc[3];
        #pragma unroll
        for (int rr = 0; rr < 4; ++rr) {
            float4 o;
            o.x = m0 + acc[rr][0]; o.y = m1 + acc[rr][1];
            o.z = m2 + acc[rr][2]; o.w = m3 + acc[rr][3];
            reinterpret_cast<float4*>(out)[rbase + 4*wv + rr] = o;
        }
    }
}

extern "C" void kernel_launch(void* const* d_in, const int* in_sizes, int n_in,
                              void* d_out, int out_size, void* d_ws, size_t ws_size,
                              hipStream_t stream) {
    const float* x  = (const float*)d_in[0];
    const float* tx = (const float*)d_in[1];
    const float* ty = (const float*)d_in[2];
    const float* ls = (const float*)d_in[3];
    const float* mc = (const float*)d_in[4];
    const float* tf = (const float*)d_in[5];
    const float* tv = (const float*)d_in[6];
    const float* tn = (const float*)d_in[7];
    const float* nz = (const float*)d_in[8];

    float* ws    = (float*)d_ws;
    float* a     = ws + OFF_A;
    float* anorm = ws + OFF_ANORM;
    float* r     = ws + OFF_R;
    float* w     = ws + OFF_W;
    float* B     = ws + OFF_B;
    float* gp    = ws + OFF_GP;
    float* dp    = ws + OFF_DP;
    int*   flags = (int*)(ws + OFF_FLAGS);

    k_prep<<<NTR/256, 256, 0, stream>>>(tx, ty, ls, mc, a, anorm, r, flags);

    void* args[] = { (void*)&a, (void*)&anorm, (void*)&r, (void*)&w,
                     (void*)&gp, (void*)&dp, (void*)&B, (void*)&flags,
                     (void*)&tf, (void*)&tv, (void*)&tn, (void*)&nz };
    hipLaunchCooperativeKernel((void*)k_pcg, dim3(NBLK), dim3(256), args, 0, stream);

    k_final<<<MTE/16, 256, 0, stream>>>(x, ls, a, anorm, B, mc, (float*)d_out);
}

// Round 4
// 132.031 us; speedup vs baseline: 11.6406x; 4.8434x over previous
//
#include <hip/hip_runtime.h>
#include <math.h>

#define NTR 2048
#define MTE 4096
#define DIM 16
#define TT 4
#define NT 8192          // NTR * TT
#define KIT 28           // max preconditioned PIPECG iterations
#define NBLK 256         // persistent blocks (1 per CU)
#define ROWS 8           // train rows per block
#define TOL2 1e-9f       // exit: gamma <= TOL2 * gamma0

// workspace layout (float offsets)
#define OFF_A     0                       // scaled train coords  NTR x DIM
#define OFF_ANORM (OFF_A + NTR*DIM)       // row norms            NTR
#define OFF_R     (OFF_ANORM + NTR)       // initial residual (y) NT
#define OFF_M     (OFF_R + NT)            // published matvec input, x2 parity
#define OFF_B     (OFF_M + 2*NT)          // A_mat @ Kt           NT
#define OFF_GP    (OFF_B + NT)            // gamma partials       2*NBLK
#define OFF_DP    (OFF_GP + 2*NBLK)       // delta partials       2*NBLK
#define OFF_FLAGS (OFF_DP + 2*NBLK)       // barrier flags        NBLK ints

__global__ void k_prep(const float* __restrict__ tx, const float* __restrict__ ty,
                       const float* __restrict__ ls, const float* __restrict__ mc,
                       float* __restrict__ a, float* __restrict__ anorm,
                       float* __restrict__ r, int* __restrict__ flags) {
    int n = blockIdx.x * 256 + threadIdx.x;   // grid covers NTR exactly
    if (n < NBLK) flags[n] = 0;               // re-zero barrier flags each launch
    float an = 0.f;
    #pragma unroll
    for (int d = 0; d < DIM; ++d) {
        float v = tx[n*DIM + d] / ls[d];
        a[n*DIM + d] = v;
        an = fmaf(v, v, an);
    }
    anorm[n] = an;
    float4 yv;
    yv.x = ty[n*4+0] - mc[0];
    yv.y = ty[n*4+1] - mc[1];
    yv.z = ty[n*4+2] - mc[2];
    yv.w = ty[n*4+3] - mc[3];
    reinterpret_cast<float4*>(r)[n] = yv;
}

// Grid barrier: write-through atomics only, no cache-writeback fences.
// Publisher: s_waitcnt vmcnt(0) guarantees prior write-through atomic stores
// are at the coherence point, then relaxed flag store. Wave 0 polls 4 packed
// flags/lane; one acquire load after success invalidates stale L1/L2 lines so
// subsequent plain vector loads of the published data are fresh.
__device__ __forceinline__ void gbar(int* __restrict__ flags, int b, int tid, int gen) {
    if (tid < 64) {
        if (tid == 0) {
            asm volatile("s_waitcnt vmcnt(0)" ::: "memory");
            __hip_atomic_store(&flags[b], gen, __ATOMIC_RELAXED, __HIP_MEMORY_SCOPE_AGENT);
        }
        const int base = tid * 4;
        for (;;) {
            int f0 = __hip_atomic_load(&flags[base+0], __ATOMIC_RELAXED, __HIP_MEMORY_SCOPE_AGENT);
            int f1 = __hip_atomic_load(&flags[base+1], __ATOMIC_RELAXED, __HIP_MEMORY_SCOPE_AGENT);
            int f2 = __hip_atomic_load(&flags[base+2], __ATOMIC_RELAXED, __HIP_MEMORY_SCOPE_AGENT);
            int f3 = __hip_atomic_load(&flags[base+3], __ATOMIC_RELAXED, __HIP_MEMORY_SCOPE_AGENT);
            if (__all((f0 >= gen) & (f1 >= gen) & (f2 >= gen) & (f3 >= gen))) break;
            __builtin_amdgcn_s_sleep(2);
        }
        (void)__hip_atomic_load(&flags[b], __ATOMIC_ACQUIRE, __HIP_MEMORY_SCOPE_AGENT);
    }
    __syncthreads();
}

// Persistent block-Jacobi-preconditioned pipelined CG (Ghysels-Vanroose).
// M^-1 = I (x) (Kt+D)^-1 via Sherman-Morrison. One barrier per iteration.
__global__ __launch_bounds__(256, 1) void k_pcg(
    const float* __restrict__ a, const float* __restrict__ anorm,
    const float* __restrict__ r0g, float* __restrict__ mbuf,
    float* __restrict__ gpart, float* __restrict__ dpart,
    float* __restrict__ Bout, int* __restrict__ flags,
    const float* __restrict__ tf, const float* __restrict__ tv,
    const float* __restrict__ tn, const float* __restrict__ nz)
{
    __shared__ float KxxS[ROWS][NTR];      // 64 KB
    __shared__ float4 qS[NTR];             // 32 KB : Kt * m per train point
    __shared__ float arowS[ROWS][DIM];
    __shared__ float anormS[ROWS];
    __shared__ float uSm[32];              // kron-matvec result slice
    __shared__ float xSl[32], rSl[32], uSl[32], wSl[32];
    __shared__ float pSl[32], sSl[32], zSl[32], qSl[32], mSl[32];
    __shared__ float scal[2];

    const int tid = threadIdx.x;
    const int b = blockIdx.x;
    const int wv = tid >> 6, lane = tid & 63;
    const int i0 = b * ROWS;
    const int sl = lane & 31;              // slice element this lane mirrors
    const int pbase = lane & ~3;           // first lane of this point's 4-group

    const float f0=tf[0], f1=tf[1], f2=tf[2], f3=tf[3];
    const float K00=fmaf(f0,f0,tv[0]), K01=f0*f1, K02=f0*f2, K03=f0*f3;
    const float K11=fmaf(f1,f1,tv[1]), K12=f1*f2, K13=f1*f3;
    const float K22=fmaf(f2,f2,tv[2]), K23=f2*f3;
    const float K33=fmaf(f3,f3,tv[3]);
    const float dz = nz[0];
    const int   t  = lane & 3;
    const float dn_t = tn[t] + dz;
    // C = (Kt + D)^-1, row t, via Sherman-Morrison (branchless selects)
    const float g0v=tv[0]+tn[0]+dz, g1v=tv[1]+tn[1]+dz, g2v=tv[2]+tn[2]+dz, g3v=tv[3]+tn[3]+dz;
    const float c0=1.f/g0v, c1=1.f/g1v, c2=1.f/g2v, c3=1.f/g3v;
    const float up0=c0*f0, up1=c1*f1, up2=c2*f2, up3=c3*f3;
    const float rden = 1.f/(1.f + f0*up0 + f1*up1 + f2*up2 + f3*up3);
    const float upt = (t==0)?up0:(t==1)?up1:(t==2)?up2:up3;
    const float Ct0 = ((t==0)?c0:0.f) - upt*up0*rden;
    const float Ct1 = ((t==1)?c1:0.f) - upt*up1*rden;
    const float Ct2 = ((t==2)?c2:0.f) - upt*up2*rden;
    const float Ct3 = ((t==3)?c3:0.f) - upt*up3*rden;

    if (tid < ROWS*DIM) arowS[tid >> 4][tid & 15] = a[i0*DIM + tid];
    if (tid < ROWS) anormS[tid] = anorm[i0 + tid];
    __syncthreads();

    // build own Kxx rows in LDS
    for (int j = tid; j < NTR; j += 256) {
        const float4* aj4 = reinterpret_cast<const float4*>(a + j*DIM);
        float4 A0=aj4[0], A1=aj4[1], A2=aj4[2], A3=aj4[3];
        float an = anorm[j];
        #pragma unroll
        for (int rr = 0; rr < ROWS; ++rr) {
            float dot;
            dot = arowS[rr][0]*A0.x;            dot = fmaf(arowS[rr][1], A0.y, dot);
            dot = fmaf(arowS[rr][2], A0.z, dot); dot = fmaf(arowS[rr][3], A0.w, dot);
            dot = fmaf(arowS[rr][4], A1.x, dot); dot = fmaf(arowS[rr][5], A1.y, dot);
            dot = fmaf(arowS[rr][6], A1.z, dot); dot = fmaf(arowS[rr][7], A1.w, dot);
            dot = fmaf(arowS[rr][8], A2.x, dot); dot = fmaf(arowS[rr][9], A2.y, dot);
            dot = fmaf(arowS[rr][10],A2.z, dot); dot = fmaf(arowS[rr][11],A2.w, dot);
            dot = fmaf(arowS[rr][12],A3.x, dot); dot = fmaf(arowS[rr][13],A3.y, dot);
            dot = fmaf(arowS[rr][14],A3.z, dot); dot = fmaf(arowS[rr][15],A3.w, dot);
            float d2 = anormS[rr] + an - 2.f*dot;
            KxxS[rr][j] = __expf(-0.5f * fmaxf(d2, 0.f));
        }
    }
    __syncthreads();

    // uSm_slice = (Kxx (x) Kt) * src
    auto matvec = [&](const float* __restrict__ src) {
        const float4* src4 = reinterpret_cast<const float4*>(src);
        for (int j = tid; j < NTR; j += 256) {
            float4 v = src4[j];
            float4 q;
            q.x = K00*v.x + K01*v.y + K02*v.z + K03*v.w;
            q.y = K01*v.x + K11*v.y + K12*v.z + K13*v.w;
            q.z = K02*v.x + K12*v.y + K22*v.z + K23*v.w;
            q.w = K03*v.x + K13*v.y + K23*v.z + K33*v.w;
            qS[j] = q;
        }
        __syncthreads();
        float a00=0,a01=0,a02=0,a03=0,a10=0,a11=0,a12=0,a13=0;
        const int r0_ = 2*wv, r1_ = r0_ + 1;
        for (int jb = 0; jb < NTR/64; ++jb) {
            int j = jb*64 + lane;
            float4 q = qS[j];
            float k0 = KxxS[r0_][j], k1 = KxxS[r1_][j];
            a00 = fmaf(k0,q.x,a00); a01 = fmaf(k0,q.y,a01);
            a02 = fmaf(k0,q.z,a02); a03 = fmaf(k0,q.w,a03);
            a10 = fmaf(k1,q.x,a10); a11 = fmaf(k1,q.y,a11);
            a12 = fmaf(k1,q.z,a12); a13 = fmaf(k1,q.w,a13);
        }
        #pragma unroll
        for (int off = 32; off; off >>= 1) {
            a00 += __shfl_down(a00,off); a01 += __shfl_down(a01,off);
            a02 += __shfl_down(a02,off); a03 += __shfl_down(a03,off);
            a10 += __shfl_down(a10,off); a11 += __shfl_down(a11,off);
            a12 += __shfl_down(a12,off); a13 += __shfl_down(a13,off);
        }
        if (lane == 0) {
            uSm[r0_*4+0]=a00; uSm[r0_*4+1]=a01; uSm[r0_*4+2]=a02; uSm[r0_*4+3]=a03;
            uSm[r1_*4+0]=a10; uSm[r1_*4+1]=a11; uSm[r1_*4+2]=a12; uSm[r1_*4+3]=a13;
        }
        __syncthreads();
    };

    int gen = 0;

    // ---- phase A: r = b, u = C r; publish u (matvec input 0) + gamma0 partial
    if (wv == 0) {
        float rv = (lane < 32) ? r0g[i0*TT + lane] : 0.f;
        float r0s = __shfl(rv, pbase+0), r1s = __shfl(rv, pbase+1);
        float r2s = __shfl(rv, pbase+2), r3s = __shfl(rv, pbase+3);
        float uv = Ct0*r0s + Ct1*r1s + Ct2*r2s + Ct3*r3s;
        if (lane < 32) {
            rSl[lane]=rv; uSl[lane]=uv;
            xSl[lane]=0.f; pSl[lane]=0.f; sSl[lane]=0.f; zSl[lane]=0.f; qSl[lane]=0.f;
            __hip_atomic_store(&mbuf[0*NT + i0*TT + lane], uv,
                               __ATOMIC_RELAXED, __HIP_MEMORY_SCOPE_AGENT);
        }
        float g = (lane < 32) ? rv*uv : 0.f;
        #pragma unroll
        for (int off = 32; off; off >>= 1) g += __shfl_down(g, off);
        if (lane == 0)
            __hip_atomic_store(&gpart[b], g, __ATOMIC_RELAXED, __HIP_MEMORY_SCOPE_AGENT);
    }
    gbar(flags, b, tid, ++gen);

    // ---- phase B: w = A u; delta0 partial; m0 = C w; publish m0 (parity 1)
    matvec(mbuf + 0*NT);
    if (wv == 0) {
        float uv = uSl[sl];
        float wn = uSm[sl] + dn_t * uv;
        float w0s = __shfl(wn, pbase+0), w1s = __shfl(wn, pbase+1);
        float w2s = __shfl(wn, pbase+2), w3s = __shfl(wn, pbase+3);
        float mn = Ct0*w0s + Ct1*w1s + Ct2*w2s + Ct3*w3s;
        if (lane < 32) {
            wSl[lane]=wn; mSl[lane]=mn;
            __hip_atomic_store(&mbuf[1*NT + i0*TT + lane], mn,
                               __ATOMIC_RELAXED, __HIP_MEMORY_SCOPE_AGENT);
        }
        float dl = (lane < 32) ? wn*uv : 0.f;
        #pragma unroll
        for (int off = 32; off; off >>= 1) dl += __shfl_down(dl, off);
        if (lane == 0)
            __hip_atomic_store(&dpart[b], dl, __ATOMIC_RELAXED, __HIP_MEMORY_SCOPE_AGENT);
    }
    gbar(flags, b, tid, ++gen);

    // ---- main loop: 1 barrier per iteration
    float gamma_prev = 1.f, alpha_prev = 1.f, gamma0 = 0.f;
    float g1h = 1e30f, g2h = 1e30f;
    for (int it = 0; it < KIT; ++it) {
        const int ps = it & 1;             // partial slot to read; mbuf write slot
        if (wv == 0) {
            float g = 0.f, dl = 0.f;
            for (int tq = lane; tq < NBLK; tq += 64) {
                g  += gpart[ps*NBLK + tq];
                dl += dpart[ps*NBLK + tq];
            }
            #pragma unroll
            for (int off = 32; off; off >>= 1) { g += __shfl_down(g,off); dl += __shfl_down(dl,off); }
            if (lane == 0) { scal[0] = g; scal[1] = dl; }
        }
        __syncthreads();
        float gam = scal[0], del = scal[1];
        if (it == 0) gamma0 = gam;
        if (!(gam > TOL2 * gamma0)) break;                 // converged / NaN
        if (it >= 8 && gam > 0.2f * g2h) break;            // fp32 stagnation
        float beta, alph;
        if (it == 0) { beta = 0.f; alph = gam / del; }
        else {
            beta = gam / gamma_prev;
            float den = del - beta * gam / alpha_prev;
            if (!(fabsf(den) > 1e-37f)) break;
            alph = gam / den;
        }

        matvec(mbuf + (ps^1)*NT);          // n = kron * m_it

        if (wv == 0) {
            float mv = mSl[sl];
            float nv = uSm[sl] + dn_t * mv;            // full A m
            float zv = fmaf(beta, zSl[sl], nv);
            float qv = fmaf(beta, qSl[sl], mv);
            float sv = fmaf(beta, sSl[sl], wSl[sl]);
            float pv = fmaf(beta, pSl[sl], uSl[sl]);
            float xv = fmaf( alph, pv, xSl[sl]);
            float rv = fmaf(-alph, sv, rSl[sl]);
            float uv = fmaf(-alph, qv, uSl[sl]);
            float wn = fmaf(-alph, zv, wSl[sl]);
            float w0s = __shfl(wn, pbase+0), w1s = __shfl(wn, pbase+1);
            float w2s = __shfl(wn, pbase+2), w3s = __shfl(wn, pbase+3);
            float mn = Ct0*w0s + Ct1*w1s + Ct2*w2s + Ct3*w3s;
            if (lane < 32) {
                zSl[lane]=zv; qSl[lane]=qv; sSl[lane]=sv; pSl[lane]=pv;
                xSl[lane]=xv; rSl[lane]=rv; uSl[lane]=uv; wSl[lane]=wn; mSl[lane]=mn;
                __hip_atomic_store(&mbuf[ps*NT + i0*TT + lane], mn,
                                   __ATOMIC_RELAXED, __HIP_MEMORY_SCOPE_AGENT);
            }
            float g = (lane < 32) ? rv*uv : 0.f;
            float dl = (lane < 32) ? wn*uv : 0.f;
            #pragma unroll
            for (int off = 32; off; off >>= 1) { g += __shfl_down(g,off); dl += __shfl_down(dl,off); }
            if (lane == 0) {
                __hip_atomic_store(&gpart[(ps^1)*NBLK + b], g,  __ATOMIC_RELAXED, __HIP_MEMORY_SCOPE_AGENT);
                __hip_atomic_store(&dpart[(ps^1)*NBLK + b], dl, __ATOMIC_RELAXED, __HIP_MEMORY_SCOPE_AGENT);
            }
        }
        gamma_prev = gam; alpha_prev = alph;
        g2h = g1h; g1h = gam;
        gbar(flags, b, tid, ++gen);
    }

    // ---- tail: B slice = (x reshaped N x T) @ Kt  (slice-local)
    __syncthreads();
    if (tid < ROWS) {
        float x0 = xSl[tid*4+0], x1 = xSl[tid*4+1], x2 = xSl[tid*4+2], x3 = xSl[tid*4+3];
        float4 Bv;
        Bv.x = K00*x0 + K01*x1 + K02*x2 + K03*x3;
        Bv.y = K01*x0 + K11*x1 + K12*x2 + K13*x3;
        Bv.z = K02*x0 + K12*x1 + K22*x2 + K23*x3;
        Bv.w = K03*x0 + K13*x1 + K23*x2 + K33*x3;
        reinterpret_cast<float4*>(Bout)[i0 + tid] = Bv;
    }
}

// mean[i,t] = mc[t] + sum_j exp(-0.5 d2(i,j)) * B[j,t]
__global__ __launch_bounds__(256) void k_final(
    const float* __restrict__ x, const float* __restrict__ ls,
    const float* __restrict__ a, const float* __restrict__ anorm,
    const float* __restrict__ B, const float* __restrict__ mc,
    float* __restrict__ out)
{
    __shared__ float4 Bl[NTR];             // 32 KB
    __shared__ float xrS[16][DIM];
    __shared__ float xnS[16];
    int tid = threadIdx.x;
    int rbase = blockIdx.x * 16;
    for (int j = tid; j < NTR; j += 256)
        Bl[j] = reinterpret_cast<const float4*>(B)[j];
    {
        int row = tid >> 4, d = tid & 15;  // 256 threads = 16 rows x 16 dims
        float v = x[(rbase + row)*DIM + d] / ls[d];
        xrS[row][d] = v;
    }
    __syncthreads();
    if (tid < 16) {
        float s = 0.f;
        #pragma unroll
        for (int d = 0; d < DIM; ++d) s = fmaf(xrS[tid][d], xrS[tid][d], s);
        xnS[tid] = s;
    }
    __syncthreads();
    int wv = tid >> 6, lane = tid & 63;
    float acc[4][4];
    #pragma unroll
    for (int i = 0; i < 4; ++i)
        #pragma unroll
        for (int t = 0; t < 4; ++t) acc[i][t] = 0.f;
    for (int jb = 0; jb < NTR/64; ++jb) {
        int j = jb*64 + lane;
        const float4* aj4 = reinterpret_cast<const float4*>(a + j*DIM);
        float4 A0=aj4[0], A1=aj4[1], A2=aj4[2], A3=aj4[3];
        float an = anorm[j];
        float4 Bj = Bl[j];
        #pragma unroll
        for (int rr = 0; rr < 4; ++rr) {
            int row = 4*wv + rr;
            float dot;
            dot = xrS[row][0]*A0.x;             dot = fmaf(xrS[row][1], A0.y, dot);
            dot = fmaf(xrS[row][2], A0.z, dot);  dot = fmaf(xrS[row][3], A0.w, dot);
            dot = fmaf(xrS[row][4], A1.x, dot);  dot = fmaf(xrS[row][5], A1.y, dot);
            dot = fmaf(xrS[row][6], A1.z, dot);  dot = fmaf(xrS[row][7], A1.w, dot);
            dot = fmaf(xrS[row][8], A2.x, dot);  dot = fmaf(xrS[row][9], A2.y, dot);
            dot = fmaf(xrS[row][10],A2.z, dot);  dot = fmaf(xrS[row][11],A2.w, dot);
            dot = fmaf(xrS[row][12],A3.x, dot);  dot = fmaf(xrS[row][13],A3.y, dot);
            dot = fmaf(xrS[row][14],A3.z, dot);  dot = fmaf(xrS[row][15],A3.w, dot);
            float d2 = xnS[row] + an - 2.f*dot;
            float e = __expf(-0.5f * fmaxf(d2, 0.f));
            acc[rr][0] = fmaf(e, Bj.x, acc[rr][0]);
            acc[rr][1] = fmaf(e, Bj.y, acc[rr][1]);
            acc[rr][2] = fmaf(e, Bj.z, acc[rr][2]);
            acc[rr][3] = fmaf(e, Bj.w, acc[rr][3]);
        }
    }
    #pragma unroll
    for (int off = 32; off; off >>= 1)
        #pragma unroll
        for (int rr = 0; rr < 4; ++rr) {
            acc[rr][0] += __shfl_down(acc[rr][0], off);
            acc[rr][1] += __shfl_down(acc[rr][1], off);
            acc[rr][2] += __shfl_down(acc[rr][2], off);
            acc[rr][3] += __shfl_down(acc[rr][3], off);
        }
    if (lane == 0) {
        float m0 = mc[0], m1 = mc[1], m2 = mc[2], m3 = mc[3];
        #pragma unroll
        for (int rr = 0; rr < 4; ++rr) {
            float4 o;
            o.x = m0 + acc[rr][0]; o.y = m1 + acc[rr][1];
            o.z = m2 + acc[rr][2]; o.w = m3 + acc[rr][3];
            reinterpret_cast<float4*>(out)[rbase + 4*wv + rr] = o;
        }
    }
}

extern "C" void kernel_launch(void* const* d_in, const int* in_sizes, int n_in,
                              void* d_out, int out_size, void* d_ws, size_t ws_size,
                              hipStream_t stream) {
    const float* x  = (const float*)d_in[0];
    const float* tx = (const float*)d_in[1];
    const float* ty = (const float*)d_in[2];
    const float* ls = (const float*)d_in[3];
    const float* mc = (const float*)d_in[4];
    const float* tf = (const float*)d_in[5];
    const float* tv = (const float*)d_in[6];
    const float* tn = (const float*)d_in[7];
    const float* nz = (const float*)d_in[8];

    float* ws    = (float*)d_ws;
    float* a     = ws + OFF_A;
    float* anorm = ws + OFF_ANORM;
    float* r     = ws + OFF_R;
    float* m     = ws + OFF_M;
    float* B     = ws + OFF_B;
    float* gp    = ws + OFF_GP;
    float* dp    = ws + OFF_DP;
    int*   flags = (int*)(ws + OFF_FLAGS);

    k_prep<<<NTR/256, 256, 0, stream>>>(tx, ty, ls, mc, a, anorm, r, flags);

    void* args[] = { (void*)&a, (void*)&anorm, (void*)&r, (void*)&m,
                     (void*)&gp, (void*)&dp, (void*)&B, (void*)&flags,
                     (void*)&tf, (void*)&tv, (void*)&tn, (void*)&nz };
    hipLaunchCooperativeKernel((void*)k_pcg, dim3(NBLK), dim3(256), args, 0, stream);

    k_final<<<MTE/16, 256, 0, stream>>>(x, ls, a, anorm, B, mc, (float*)d_out);
}

// Round 5
// 108.453 us; speedup vs baseline: 14.1713x; 1.2174x over previous
//
#include <hip/hip_runtime.h>
#include <math.h>

#define NTR 2048
#define MTE 4096
#define DIM 16
#define TT 4
#define NT 8192          // NTR * TT
#define KIT 26           // max preconditioned PIPECG iterations
#define NBLK 256         // persistent blocks (1 per CU)
#define ROWS 8           // train rows per block
#define TOL2 1e-8f       // exit: gamma <= TOL2 * gamma0

typedef unsigned long long u64;

// workspace layout (float offsets)
#define OFF_A     0                       // scaled train coords  NTR x DIM
#define OFF_ANORM (OFF_A + NTR*DIM)       // row norms            NTR
#define OFF_M     (OFF_ANORM + NTR)       // published matvec input, x2 parity
#define OFF_B     (OFF_M + 2*NT)          // A_mat @ Kt           NT
#define OFF_FG    (OFF_B + NT)            // gamma flag+payload   NBLK u64 (even off)
#define OFF_FD    (OFF_FG + 2*NBLK)       // delta flag+payload   NBLK u64

__global__ void k_zero(u64* __restrict__ f) {
    int i = threadIdx.x;                  // 1 block x 256 threads, 512 u64
    f[i] = 0ULL; f[i + 256] = 0ULL;
}

// Grid barrier with payload: publisher packs {gen|float} into two 64-bit
// atomics (gamma, delta partials). Pollers (wave 0, 4 blocks/lane) discover
// the generation AND collect the partials in the same loads, then butterfly-
// reduce into scal[] — no separate partial-read round trip. s_waitcnt
// vmcnt(0) before the flag store guarantees prior write-through atomic
// stores (all issued by wave 0) are at the coherence point; the acquire
// load after success invalidates stale lines for subsequent plain reads.
__device__ __forceinline__ void gbar(u64* __restrict__ fG, u64* __restrict__ fD,
                                     int b, int tid, int gen,
                                     float gv, float dv, float* __restrict__ scal)
{
    if (tid < 64) {
        if (tid == 0) {
            u64 pg = ((u64)(unsigned)gen << 32) | (u64)__float_as_uint(gv);
            u64 pd = ((u64)(unsigned)gen << 32) | (u64)__float_as_uint(dv);
            asm volatile("s_waitcnt vmcnt(0)" ::: "memory");
            __hip_atomic_store(&fG[b], pg, __ATOMIC_RELAXED, __HIP_MEMORY_SCOPE_AGENT);
            __hip_atomic_store(&fD[b], pd, __ATOMIC_RELAXED, __HIP_MEMORY_SCOPE_AGENT);
        }
        const int base = tid * 4;
        float gs, ds;
        for (;;) {
            u64 a0 = __hip_atomic_load(&fG[base+0], __ATOMIC_RELAXED, __HIP_MEMORY_SCOPE_AGENT);
            u64 a1 = __hip_atomic_load(&fG[base+1], __ATOMIC_RELAXED, __HIP_MEMORY_SCOPE_AGENT);
            u64 a2 = __hip_atomic_load(&fG[base+2], __ATOMIC_RELAXED, __HIP_MEMORY_SCOPE_AGENT);
            u64 a3 = __hip_atomic_load(&fG[base+3], __ATOMIC_RELAXED, __HIP_MEMORY_SCOPE_AGENT);
            u64 d0 = __hip_atomic_load(&fD[base+0], __ATOMIC_RELAXED, __HIP_MEMORY_SCOPE_AGENT);
            u64 d1 = __hip_atomic_load(&fD[base+1], __ATOMIC_RELAXED, __HIP_MEMORY_SCOPE_AGENT);
            u64 d2 = __hip_atomic_load(&fD[base+2], __ATOMIC_RELAXED, __HIP_MEMORY_SCOPE_AGENT);
            u64 d3 = __hip_atomic_load(&fD[base+3], __ATOMIC_RELAXED, __HIP_MEMORY_SCOPE_AGENT);
            int ok = ((int)(a0>>32) >= gen) & ((int)(a1>>32) >= gen)
                   & ((int)(a2>>32) >= gen) & ((int)(a3>>32) >= gen)
                   & ((int)(d0>>32) >= gen) & ((int)(d1>>32) >= gen)
                   & ((int)(d2>>32) >= gen) & ((int)(d3>>32) >= gen);
            if (__all(ok)) {
                gs = __uint_as_float((unsigned)a0) + __uint_as_float((unsigned)a1)
                   + __uint_as_float((unsigned)a2) + __uint_as_float((unsigned)a3);
                ds = __uint_as_float((unsigned)d0) + __uint_as_float((unsigned)d1)
                   + __uint_as_float((unsigned)d2) + __uint_as_float((unsigned)d3);
                break;
            }
            __builtin_amdgcn_s_sleep(2);
        }
        #pragma unroll
        for (int off = 32; off; off >>= 1) {
            gs += __shfl_down(gs, off);
            ds += __shfl_down(ds, off);
        }
        if (tid == 0) { scal[0] = gs; scal[1] = ds; }
        (void)__hip_atomic_load(&fG[b], __ATOMIC_ACQUIRE, __HIP_MEMORY_SCOPE_AGENT);
    }
    __syncthreads();
}

// One persistent kernel: prep + block-Jacobi-preconditioned pipelined CG
// (Ghysels-Vanroose, M^-1 = I (x) (Kt+D)^-1 via Sherman-Morrison, 1 barrier
// per iteration) + posterior-mean epilogue. All cross-block global stores
// are issued by wave 0 (so the publisher's vmcnt(0) covers them).
__global__ __launch_bounds__(256, 1) void k_pcg(
    const float* __restrict__ tx, const float* __restrict__ ty,
    const float* __restrict__ xte, const float* __restrict__ ls,
    const float* __restrict__ mc,
    const float* __restrict__ tf, const float* __restrict__ tv,
    const float* __restrict__ tn, const float* __restrict__ nz,
    float* __restrict__ ag, float* __restrict__ anormg,
    float* __restrict__ mbuf, float* __restrict__ Bout,
    u64* __restrict__ fG, u64* __restrict__ fD,
    float* __restrict__ out)
{
    __shared__ float KxxS[ROWS][NTR];      // 64 KB
    __shared__ float4 qS[NTR];             // 32 KB : Kt*m staging; later B tile
    __shared__ float arowS[ROWS][DIM];
    __shared__ float anormS[ROWS];
    __shared__ float uSm[32];
    __shared__ float xSl[32], rSl[32], uSl[32], wSl[32];
    __shared__ float pSl[32], sSl[32], zSl[32], qSl[32], mSl[32];
    __shared__ float scal[2];
    __shared__ float xrS[16][DIM];
    __shared__ float xnS[16];

    const int tid = threadIdx.x;
    const int b = blockIdx.x;
    const int wv = tid >> 6, lane = tid & 63;
    const int i0 = b * ROWS;
    const int sl = lane & 31;
    const int pbase = lane & ~3;
    int gen = 0;

    const float f0=tf[0], f1=tf[1], f2=tf[2], f3=tf[3];
    const float K00=fmaf(f0,f0,tv[0]), K01=f0*f1, K02=f0*f2, K03=f0*f3;
    const float K11=fmaf(f1,f1,tv[1]), K12=f1*f2, K13=f1*f3;
    const float K22=fmaf(f2,f2,tv[2]), K23=f2*f3;
    const float K33=fmaf(f3,f3,tv[3]);
    const float dz = nz[0];
    const int   t  = lane & 3;
    const float dn_t = tn[t] + dz;
    // C = (Kt + D)^-1 row t via Sherman-Morrison
    const float g0v=tv[0]+tn[0]+dz, g1v=tv[1]+tn[1]+dz, g2v=tv[2]+tn[2]+dz, g3v=tv[3]+tn[3]+dz;
    const float c0=1.f/g0v, c1=1.f/g1v, c2=1.f/g2v, c3=1.f/g3v;
    const float up0=c0*f0, up1=c1*f1, up2=c2*f2, up3=c3*f3;
    const float rden = 1.f/(1.f + f0*up0 + f1*up1 + f2*up2 + f3*up3);
    const float upt = (t==0)?up0:(t==1)?up1:(t==2)?up2:up3;
    const float Ct0 = ((t==0)?c0:0.f) - upt*up0*rden;
    const float Ct1 = ((t==1)?c1:0.f) - upt*up1*rden;
    const float Ct2 = ((t==2)?c2:0.f) - upt*up2*rden;
    const float Ct3 = ((t==3)?c3:0.f) - upt*up3*rden;
    // Kt row t (for B = A @ Kt in the tail)
    const float Kt0 = (t==0)?K00:(t==1)?K01:(t==2)?K02:K03;
    const float Kt1 = (t==0)?K01:(t==1)?K11:(t==2)?K12:K13;
    const float Kt2 = (t==0)?K02:(t==1)?K12:(t==2)?K22:K23;
    const float Kt3 = (t==0)?K03:(t==1)?K13:(t==2)?K23:K33;

    // ---- in-kernel prep: wave 0 computes + publishes own a/anorm slice ----
    if (tid < 64) {
        #pragma unroll
        for (int e = tid; e < ROWS*DIM; e += 64) {
            int p = e >> 4, d = e & 15;
            float v = tx[(i0+p)*DIM + d] / ls[d];
            arowS[p][d] = v;
            __hip_atomic_store(&ag[(i0+p)*DIM + d], v,
                               __ATOMIC_RELAXED, __HIP_MEMORY_SCOPE_AGENT);
        }
    }
    __syncthreads();
    if (tid < ROWS) {
        float s = 0.f;
        #pragma unroll
        for (int d = 0; d < DIM; ++d) s = fmaf(arowS[tid][d], arowS[tid][d], s);
        anormS[tid] = s;
        __hip_atomic_store(&anormg[i0 + tid], s,
                           __ATOMIC_RELAXED, __HIP_MEMORY_SCOPE_AGENT);
    }
    __syncthreads();

    // ---- phase A: r = y - mc, u = C r; publish u (matvec input, parity 0) ----
    float gpart_reg = 0.f;
    if (wv == 0) {
        float rv = (lane < 32) ? (ty[i0*TT + lane] - mc[t]) : 0.f;
        float r0s = __shfl(rv, pbase+0), r1s = __shfl(rv, pbase+1);
        float r2s = __shfl(rv, pbase+2), r3s = __shfl(rv, pbase+3);
        float uv = Ct0*r0s + Ct1*r1s + Ct2*r2s + Ct3*r3s;
        if (lane < 32) {
            rSl[lane]=rv; uSl[lane]=uv;
            xSl[lane]=0.f; pSl[lane]=0.f; sSl[lane]=0.f; zSl[lane]=0.f; qSl[lane]=0.f;
            __hip_atomic_store(&mbuf[0*NT + i0*TT + lane], uv,
                               __ATOMIC_RELAXED, __HIP_MEMORY_SCOPE_AGENT);
        }
        float g = (lane < 32) ? rv*uv : 0.f;
        #pragma unroll
        for (int off = 32; off; off >>= 1) g += __shfl_down(g, off);
        gpart_reg = g;                     // valid in lane 0
    }
    gbar(fG, fD, b, tid, ++gen, gpart_reg, 0.f, scal);

    // ---- build own Kxx rows in LDS (plain loads of published a/anorm) ----
    for (int j = tid; j < NTR; j += 256) {
        const float4* aj4 = reinterpret_cast<const float4*>(ag + j*DIM);
        float4 A0=aj4[0], A1=aj4[1], A2=aj4[2], A3=aj4[3];
        float an = anormg[j];
        #pragma unroll
        for (int rr = 0; rr < ROWS; ++rr) {
            float dot;
            dot = arowS[rr][0]*A0.x;            dot = fmaf(arowS[rr][1], A0.y, dot);
            dot = fmaf(arowS[rr][2], A0.z, dot); dot = fmaf(arowS[rr][3], A0.w, dot);
            dot = fmaf(arowS[rr][4], A1.x, dot); dot = fmaf(arowS[rr][5], A1.y, dot);
            dot = fmaf(arowS[rr][6], A1.z, dot); dot = fmaf(arowS[rr][7], A1.w, dot);
            dot = fmaf(arowS[rr][8], A2.x, dot); dot = fmaf(arowS[rr][9], A2.y, dot);
            dot = fmaf(arowS[rr][10],A2.z, dot); dot = fmaf(arowS[rr][11],A2.w, dot);
            dot = fmaf(arowS[rr][12],A3.x, dot); dot = fmaf(arowS[rr][13],A3.y, dot);
            dot = fmaf(arowS[rr][14],A3.z, dot); dot = fmaf(arowS[rr][15],A3.w, dot);
            float d2 = anormS[rr] + an - 2.f*dot;
            KxxS[rr][j] = __expf(-0.5f * fmaxf(d2, 0.f));
        }
    }
    __syncthreads();

    // uSm_slice = (Kxx (x) Kt) * src
    auto matvec = [&](const float* __restrict__ src) {
        const float4* src4 = reinterpret_cast<const float4*>(src);
        for (int j = tid; j < NTR; j += 256) {
            float4 v = src4[j];
            float4 q;
            q.x = K00*v.x + K01*v.y + K02*v.z + K03*v.w;
            q.y = K01*v.x + K11*v.y + K12*v.z + K13*v.w;
            q.z = K02*v.x + K12*v.y + K22*v.z + K23*v.w;
            q.w = K03*v.x + K13*v.y + K23*v.z + K33*v.w;
            qS[j] = q;
        }
        __syncthreads();
        float a00=0,a01=0,a02=0,a03=0,a10=0,a11=0,a12=0,a13=0;
        const int r0_ = 2*wv, r1_ = r0_ + 1;
        for (int jb = 0; jb < NTR/64; ++jb) {
            int j = jb*64 + lane;
            float4 q = qS[j];
            float k0 = KxxS[r0_][j], k1 = KxxS[r1_][j];
            a00 = fmaf(k0,q.x,a00); a01 = fmaf(k0,q.y,a01);
            a02 = fmaf(k0,q.z,a02); a03 = fmaf(k0,q.w,a03);
            a10 = fmaf(k1,q.x,a10); a11 = fmaf(k1,q.y,a11);
            a12 = fmaf(k1,q.z,a12); a13 = fmaf(k1,q.w,a13);
        }
        #pragma unroll
        for (int off = 32; off; off >>= 1) {
            a00 += __shfl_down(a00,off); a01 += __shfl_down(a01,off);
            a02 += __shfl_down(a02,off); a03 += __shfl_down(a03,off);
            a10 += __shfl_down(a10,off); a11 += __shfl_down(a11,off);
            a12 += __shfl_down(a12,off); a13 += __shfl_down(a13,off);
        }
        if (lane == 0) {
            uSm[r0_*4+0]=a00; uSm[r0_*4+1]=a01; uSm[r0_*4+2]=a02; uSm[r0_*4+3]=a03;
            uSm[r1_*4+0]=a10; uSm[r1_*4+1]=a11; uSm[r1_*4+2]=a12; uSm[r1_*4+3]=a13;
        }
        __syncthreads();
    };

    // ---- phase B: w = A u; m0 = C w; publish m0 (parity 1) + (gamma, delta) ----
    matvec(mbuf + 0*NT);
    float dpart_reg = 0.f;
    if (wv == 0) {
        float uv = uSl[sl];
        float wn = uSm[sl] + dn_t * uv;
        float w0s = __shfl(wn, pbase+0), w1s = __shfl(wn, pbase+1);
        float w2s = __shfl(wn, pbase+2), w3s = __shfl(wn, pbase+3);
        float mn = Ct0*w0s + Ct1*w1s + Ct2*w2s + Ct3*w3s;
        if (lane < 32) {
            wSl[lane]=wn; mSl[lane]=mn;
            __hip_atomic_store(&mbuf[1*NT + i0*TT + lane], mn,
                               __ATOMIC_RELAXED, __HIP_MEMORY_SCOPE_AGENT);
        }
        float dl = (lane < 32) ? wn*uv : 0.f;
        #pragma unroll
        for (int off = 32; off; off >>= 1) dl += __shfl_down(dl, off);
        dpart_reg = dl;
    }
    gbar(fG, fD, b, tid, ++gen, gpart_reg, dpart_reg, scal);

    // ---- main loop: 1 barrier per iteration, scalars arrive with the flags ----
    float gamma_prev = 1.f, alpha_prev = 1.f, gamma0 = 0.f;
    float g1h = 1e30f, g2h = 1e30f;
    for (int it = 0; it < KIT; ++it) {
        const int ps = it & 1;
        float gam = scal[0], del = scal[1];
        if (it == 0) gamma0 = gam;
        if (!(gam > TOL2 * gamma0)) break;                 // converged / NaN
        if (it >= 6 && gam > 0.25f * g2h) break;           // fp32 stagnation
        float beta, alph;
        if (it == 0) { beta = 0.f; alph = gam / del; }
        else {
            beta = gam / gamma_prev;
            float den = del - beta * gam / alpha_prev;
            if (!(fabsf(den) > 1e-37f)) break;
            alph = gam / den;
        }

        matvec(mbuf + (ps^1)*NT);          // kron * m_it

        float gnew = 0.f, dnew = 0.f;
        if (wv == 0) {
            float mv = mSl[sl];
            float nv = uSm[sl] + dn_t * mv;            // full A m
            float zv = fmaf(beta, zSl[sl], nv);
            float qv = fmaf(beta, qSl[sl], mv);
            float sv = fmaf(beta, sSl[sl], wSl[sl]);
            float pv = fmaf(beta, pSl[sl], uSl[sl]);
            float xv = fmaf( alph, pv, xSl[sl]);
            float rv = fmaf(-alph, sv, rSl[sl]);
            float uv = fmaf(-alph, qv, uSl[sl]);
            float wn = fmaf(-alph, zv, wSl[sl]);
            float w0s = __shfl(wn, pbase+0), w1s = __shfl(wn, pbase+1);
            float w2s = __shfl(wn, pbase+2), w3s = __shfl(wn, pbase+3);
            float mn = Ct0*w0s + Ct1*w1s + Ct2*w2s + Ct3*w3s;
            if (lane < 32) {
                zSl[lane]=zv; qSl[lane]=qv; sSl[lane]=sv; pSl[lane]=pv;
                xSl[lane]=xv; rSl[lane]=rv; uSl[lane]=uv; wSl[lane]=wn; mSl[lane]=mn;
                __hip_atomic_store(&mbuf[ps*NT + i0*TT + lane], mn,
                                   __ATOMIC_RELAXED, __HIP_MEMORY_SCOPE_AGENT);
            }
            float g  = (lane < 32) ? rv*uv : 0.f;
            float dl = (lane < 32) ? wn*uv : 0.f;
            #pragma unroll
            for (int off = 32; off; off >>= 1) { g += __shfl_down(g,off); dl += __shfl_down(dl,off); }
            gnew = g; dnew = dl;
        }
        gamma_prev = gam; alpha_prev = alph;
        g2h = g1h; g1h = gam;
        gbar(fG, fD, b, tid, ++gen, gnew, dnew, scal);
    }

    // ---- tail 1: publish B slice = (x reshaped N x T) @ Kt ----
    __syncthreads();
    if (tid < 32) {
        int p = tid >> 2;
        float bv = Kt0*xSl[p*4+0] + Kt1*xSl[p*4+1] + Kt2*xSl[p*4+2] + Kt3*xSl[p*4+3];
        __hip_atomic_store(&Bout[i0*TT + tid], bv,
                           __ATOMIC_RELAXED, __HIP_MEMORY_SCOPE_AGENT);
    }
    gbar(fG, fD, b, tid, ++gen, 0.f, 0.f, scal);

    // ---- tail 2: posterior mean for this block's 16 test rows ----
    for (int j = tid; j < NTR; j += 256)
        qS[j] = reinterpret_cast<const float4*>(Bout)[j];   // B tile (reuse qS)
    {
        int row = tid >> 4, d = tid & 15;
        xrS[row][d] = xte[(b*16 + row)*DIM + d] / ls[d];
    }
    __syncthreads();
    if (tid < 16) {
        float s = 0.f;
        #pragma unroll
        for (int d = 0; d < DIM; ++d) s = fmaf(xrS[tid][d], xrS[tid][d], s);
        xnS[tid] = s;
    }
    __syncthreads();
    float acc[4][4];
    #pragma unroll
    for (int i = 0; i < 4; ++i)
        #pragma unroll
        for (int tt = 0; tt < 4; ++tt) acc[i][tt] = 0.f;
    for (int jb = 0; jb < NTR/64; ++jb) {
        int j = jb*64 + lane;
        const float4* aj4 = reinterpret_cast<const float4*>(ag + j*DIM);
        float4 A0=aj4[0], A1=aj4[1], A2=aj4[2], A3=aj4[3];
        float an = anormg[j];
        float4 Bj = qS[j];
        #pragma unroll
        for (int rr = 0; rr < 4; ++rr) {
            int row = 4*wv + rr;
            float dot;
            dot = xrS[row][0]*A0.x;             dot = fmaf(xrS[row][1], A0.y, dot);
            dot = fmaf(xrS[row][2], A0.z, dot);  dot = fmaf(xrS[row][3], A0.w, dot);
            dot = fmaf(xrS[row][4], A1.x, dot);  dot = fmaf(xrS[row][5], A1.y, dot);
            dot = fmaf(xrS[row][6], A1.z, dot);  dot = fmaf(xrS[row][7], A1.w, dot);
            dot = fmaf(xrS[row][8], A2.x, dot);  dot = fmaf(xrS[row][9], A2.y, dot);
            dot = fmaf(xrS[row][10],A2.z, dot);  dot = fmaf(xrS[row][11],A2.w, dot);
            dot = fmaf(xrS[row][12],A3.x, dot);  dot = fmaf(xrS[row][13],A3.y, dot);
            dot = fmaf(xrS[row][14],A3.z, dot);  dot = fmaf(xrS[row][15],A3.w, dot);
            float d2 = xnS[row] + an - 2.f*dot;
            float e = __expf(-0.5f * fmaxf(d2, 0.f));
            acc[rr][0] = fmaf(e, Bj.x, acc[rr][0]);
            acc[rr][1] = fmaf(e, Bj.y, acc[rr][1]);
            acc[rr][2] = fmaf(e, Bj.z, acc[rr][2]);
            acc[rr][3] = fmaf(e, Bj.w, acc[rr][3]);
        }
    }
    #pragma unroll
    for (int off = 32; off; off >>= 1)
        #pragma unroll
        for (int rr = 0; rr < 4; ++rr) {
            acc[rr][0] += __shfl_down(acc[rr][0], off);
            acc[rr][1] += __shfl_down(acc[rr][1], off);
            acc[rr][2] += __shfl_down(acc[rr][2], off);
            acc[rr][3] += __shfl_down(acc[rr][3], off);
        }
    if (lane == 0) {
        float m0 = mc[0], m1 = mc[1], m2 = mc[2], m3 = mc[3];
        #pragma unroll
        for (int rr = 0; rr < 4; ++rr) {
            float4 o;
            o.x = m0 + acc[rr][0]; o.y = m1 + acc[rr][1];
            o.z = m2 + acc[rr][2]; o.w = m3 + acc[rr][3];
            reinterpret_cast<float4*>(out)[b*16 + 4*wv + rr] = o;
        }
    }
}

extern "C" void kernel_launch(void* const* d_in, const int* in_sizes, int n_in,
                              void* d_out, int out_size, void* d_ws, size_t ws_size,
                              hipStream_t stream) {
    const float* x  = (const float*)d_in[0];
    const float* tx = (const float*)d_in[1];
    const float* ty = (const float*)d_in[2];
    const float* ls = (const float*)d_in[3];
    const float* mc = (const float*)d_in[4];
    const float* tf = (const float*)d_in[5];
    const float* tv = (const float*)d_in[6];
    const float* tn = (const float*)d_in[7];
    const float* nz = (const float*)d_in[8];

    float* ws    = (float*)d_ws;
    float* a     = ws + OFF_A;
    float* anorm = ws + OFF_ANORM;
    float* m     = ws + OFF_M;
    float* B     = ws + OFF_B;
    u64*   fG    = (u64*)(ws + OFF_FG);
    u64*   fD    = (u64*)(ws + OFF_FD);
    float* outp  = (float*)d_out;

    k_zero<<<1, 256, 0, stream>>>(fG);     // fG and fD are contiguous

    void* args[] = { (void*)&tx, (void*)&ty, (void*)&x, (void*)&ls, (void*)&mc,
                     (void*)&tf, (void*)&tv, (void*)&tn, (void*)&nz,
                     (void*)&a, (void*)&anorm, (void*)&m, (void*)&B,
                     (void*)&fG, (void*)&fD, (void*)&outp };
    hipLaunchCooperativeKernel((void*)k_pcg, dim3(NBLK), dim3(256), args, 0, stream);
}